// Round 11
// baseline (672.535 us; speedup 1.0000x reference)
//
#include <hip/hip_runtime.h>
#include <math.h>

#define Bv 16
#define Nn 5000
#define NCc 500
#define NSs 50
#define Uu 64
#define Ff 65   // IN + U
#define CAPF 96
#define CAPC 128
#define CAPS 64
#define ROW  (Bv * Ff)           // 1040 floats per X/Y row
#define ROW4 (ROW / 4)           // 260 float4
#define TAIL4 (ROW4 - 256)       // 4
#define PAD 68                   // padded LDS row (68*4B = 272B, 16B-aligned)

// ---------------- dense -> ELL sparse build (float4 scan; n % 4 == 0) ----------------
__global__ __launch_bounds__(256) void build_ell_v4(const float* __restrict__ A, int n, int cap,
                                                    int* __restrict__ cols, float* __restrict__ vals,
                                                    int* __restrict__ cnt) {
    int row = blockIdx.x;
    __shared__ int scnt;
    if (threadIdx.x == 0) scnt = 0;
    __syncthreads();
    const float4* arow = (const float4*)(A + (size_t)row * n);
    int n4 = n >> 2;
    for (int m = threadIdx.x; m < n4; m += blockDim.x) {
        float4 v = arow[m];
        int base = m << 2;
        if (v.x != 0.0f) { int s = atomicAdd(&scnt, 1); if (s < cap) { cols[(size_t)row * cap + s] = base;     vals[(size_t)row * cap + s] = v.x; } }
        if (v.y != 0.0f) { int s = atomicAdd(&scnt, 1); if (s < cap) { cols[(size_t)row * cap + s] = base + 1; vals[(size_t)row * cap + s] = v.y; } }
        if (v.z != 0.0f) { int s = atomicAdd(&scnt, 1); if (s < cap) { cols[(size_t)row * cap + s] = base + 2; vals[(size_t)row * cap + s] = v.z; } }
        if (v.w != 0.0f) { int s = atomicAdd(&scnt, 1); if (s < cap) { cols[(size_t)row * cap + s] = base + 3; vals[(size_t)row * cap + s] = v.w; } }
    }
    __syncthreads();
    if (threadIdx.x == 0) cnt[row] = scnt < cap ? scnt : cap;
}

// scalar fallback (any n)
__global__ void build_ell(const float* __restrict__ A, int n, int cap,
                          int* __restrict__ cols, float* __restrict__ vals,
                          int* __restrict__ cnt) {
    int row = blockIdx.x;
    __shared__ int scnt;
    if (threadIdx.x == 0) scnt = 0;
    __syncthreads();
    const float* arow = A + (size_t)row * n;
    for (int m = threadIdx.x; m < n; m += blockDim.x) {
        float v = arow[m];
        if (v != 0.0f) {
            int slot = atomicAdd(&scnt, 1);
            if (slot < cap) {
                cols[(size_t)row * cap + slot] = m;
                vals[(size_t)row * cap + slot] = v;
            }
        }
    }
    __syncthreads();
    if (threadIdx.x == 0) cnt[row] = scnt < cap ? scnt : cap;
}

// ---------------- xc[b,c] = sum_n afc[c,n] * xi[b,n] ----------------
__global__ __launch_bounds__(256) void xc_kernel(const float* __restrict__ afc,
                                                 const float* __restrict__ xi,
                                                 float* __restrict__ xc) {
    int c = blockIdx.x;
    float loc[Bv];
#pragma unroll
    for (int b = 0; b < Bv; ++b) loc[b] = 0.0f;
    const float* arow = afc + (size_t)c * Nn;
    for (int n = threadIdx.x; n < Nn; n += blockDim.x) {
        float a = arow[n];
        if (a != 0.0f) {
#pragma unroll
            for (int b = 0; b < Bv; ++b) loc[b] += a * xi[b * Nn + n];
        }
    }
    __shared__ float red[Bv][4];
#pragma unroll
    for (int b = 0; b < Bv; ++b) {
        float v = loc[b];
        for (int off = 32; off; off >>= 1) v += __shfl_down(v, off);
        if ((threadIdx.x & 63) == 0) red[b][threadIdx.x >> 6] = v;
    }
    __syncthreads();
    if (threadIdx.x < Bv) {
        float v = 0.0f;
        for (int w = 0; w < 4; ++w) v += red[threadIdx.x][w];
        xc[threadIdx.x * NCc + c] = v;  // (B, NC)
    }
}

// ---------------- row softmax ----------------
__global__ void softmax_rows(const float* __restrict__ M, float* __restrict__ S,
                             int cols) {
    int r = blockIdx.x;
    int t = threadIdx.x;
    float v = (t < cols) ? M[r * cols + t] : -3.4e38f;
    float m = v;
    for (int off = 32; off; off >>= 1) m = fmaxf(m, __shfl_xor(m, off));
    float e = (t < cols) ? __expf(v - m) : 0.0f;
    float s = e;
    for (int off = 32; off; off >>= 1) s += __shfl_xor(s, off);
    if (t < cols) S[r * cols + t] = e / s;
}

// tmp[c,j] = sum_k adj1[c,k] * S[k,j]
__global__ void mm_tmp(const float* __restrict__ A, const float* __restrict__ S,
                       float* __restrict__ T) {
    int idx = blockIdx.x * blockDim.x + threadIdx.x;
    if (idx >= NCc * NSs) return;
    int r = idx / NSs, c = idx % NSs;
    float s = 0.0f;
    for (int k = 0; k < NCc; ++k) s += A[r * NCc + k] * S[k * NSs + c];
    T[idx] = s;
}
__global__ void mm_adj2(const float* __restrict__ S, const float* __restrict__ T,
                        float* __restrict__ A2) {
    int idx = blockIdx.x * blockDim.x + threadIdx.x;
    if (idx >= NSs * NSs) return;
    int i = idx / NSs, j = idx % NSs;
    float s = 0.0f;
    for (int c = 0; c < NCc; ++c) s += S[c * NSs + i] * T[c * NSs + j];
    A2[idx] = s;
}
__global__ void mm_xs(const float* __restrict__ S, const float* __restrict__ xc,
                      float* __restrict__ xs) {
    int idx = blockIdx.x * blockDim.x + threadIdx.x;
    if (idx >= Bv * NSs) return;
    int b = idx / NSs, j = idx % NSs;
    float s = 0.0f;
    for (int c = 0; c < NCc; ++c) s += S[c * NSs + j] * xc[b * NCc + c];
    xs[idx] = s;
}

// ---------------- pack X[n][b][f] ----------------
__global__ void pack_x(const float* __restrict__ xf, const float* __restrict__ h,
                       float* __restrict__ X, int nodes) {
    int idx = blockIdx.x * blockDim.x + threadIdx.x;
    int total = nodes * Bv * Ff;
    if (idx >= total) return;
    int f = idx % Ff;
    int t = idx / Ff;
    int b = t % Bv;
    int n = t / Bv;
    X[idx] = (f == 0) ? xf[b * nodes + n]
                      : h[(size_t)b * nodes * Uu + n * Uu + (f - 1)];
}

// ---------------- SpMM gather only: Y[n,:] = sum_j val[j] * X[col[j],:] ----------------
// Tail (4 extra float4 of the 260-float4 row) merged INTO the main loop: lanes 0-3 of
// wave 0 carry a second accumulator instead of re-running the whole loop serially.
template <int CAP>
__global__ __launch_bounds__(256, 8) void spmm_gather(
    int nodes, const int* __restrict__ cols, const float* __restrict__ vals,
    const int* __restrict__ cnt, const float* __restrict__ X,
    float* __restrict__ Y) {
    int n = blockIdx.x;
    int tid = threadIdx.x;
    __shared__ int ncol[CAP];
    __shared__ float nval[CAP];
    int c = cnt[n];
    for (int j = tid; j < c; j += 256) {
        ncol[j] = cols[(size_t)n * CAP + j];
        nval[j] = vals[(size_t)n * CAP + j];
    }
    __syncthreads();
    float4 a0 = make_float4(0.f, 0.f, 0.f, 0.f);
    float4 a1 = make_float4(0.f, 0.f, 0.f, 0.f);
#pragma unroll 4
    for (int j = 0; j < c; ++j) {
        const float4* xr4 = (const float4*)(X + (size_t)ncol[j] * ROW);
        float av = nval[j];
        float4 v = xr4[tid];
        a0.x += av * v.x; a0.y += av * v.y; a0.z += av * v.z; a0.w += av * v.w;
        if (tid < TAIL4) {
            float4 v1 = xr4[256 + tid];
            a1.x += av * v1.x; a1.y += av * v1.y; a1.z += av * v1.z; a1.w += av * v1.w;
        }
    }
    ((float4*)(Y + (size_t)n * ROW))[tid] = a0;
    if (tid < TAIL4)
        ((float4*)(Y + (size_t)n * ROW))[256 + tid] = a1;
}

// ---------------- gate projection: x1=Y@W0+b0 ; sig -> r,u ; emit X2, u ----------------
// __launch_bounds__(256,4): cap 128 VGPR (round-5 hit 256 VGPR -> 10.7% occupancy).
// #pragma unroll 4 bounds W-load pipelining to ~16 in flight. (Measured r7: VGPR=64, 101us)
__global__ __launch_bounds__(256, 4) void proj_gate(
    int nodes, const float* __restrict__ Y,
    const float* __restrict__ W0, const float* __restrict__ b0,
    const float* __restrict__ h, const float* __restrict__ xf,
    float* __restrict__ X2, float* __restrict__ u_out) {
    int n = blockIdx.x;
    int tid = threadIdx.x;
    __shared__ float accs[Bv * PAD];
    const float* yr = Y + (size_t)n * ROW;
    for (int i = tid; i < ROW; i += 256)
        accs[(i / Ff) * PAD + (i % Ff)] = yr[i];
    __syncthreads();
    int kk = tid & 127;
    int bb = tid >> 7;   // wave-uniform
    float s[8];
    float bias = b0[kk];
#pragma unroll
    for (int w = 0; w < 8; ++w) s[w] = bias;
#pragma unroll 4
    for (int f4 = 0; f4 < 64; f4 += 4) {
        float4 wv;
        wv.x = W0[(f4 + 0) * 128 + kk];
        wv.y = W0[(f4 + 1) * 128 + kk];
        wv.z = W0[(f4 + 2) * 128 + kk];
        wv.w = W0[(f4 + 3) * 128 + kk];
#pragma unroll
        for (int w = 0; w < 8; ++w) {
            float4 av = *(const float4*)(accs + (bb + 2 * w) * PAD + f4);  // broadcast b128
            s[w] += av.x * wv.x + av.y * wv.y + av.z * wv.z + av.w * wv.w;
        }
    }
    float wt = W0[64 * 128 + kk];
#pragma unroll
    for (int w = 0; w < 8; ++w) s[w] += accs[(bb + 2 * w) * PAD + 64] * wt;
#pragma unroll
    for (int w = 0; w < 8; ++w) {
        int b = bb + 2 * w;
        float sv = 1.0f / (1.0f + __expf(-s[w]));
        if (kk < Uu) {
            float hv = h[((size_t)b * nodes + n) * Uu + kk];
            X2[((size_t)n * Bv + b) * Ff + 1 + kk] = sv * hv;
        } else {
            u_out[((size_t)b * nodes + n) * Uu + (kk - Uu)] = sv;
            if (kk == Uu) X2[((size_t)n * Bv + b) * Ff] = xf[(size_t)b * nodes + n];
        }
    }
}

// ---------------- cand projection: c=tanh(Y@W1+b1); out=u*h+(1-u)*c ----------------
__global__ __launch_bounds__(256, 4) void proj_cand(
    int nodes, const float* __restrict__ Y,
    const float* __restrict__ W1, const float* __restrict__ b1,
    const float* __restrict__ h, float* uo /* holds u, receives out */) {
    int n = blockIdx.x;
    int tid = threadIdx.x;
    __shared__ float accs[Bv * PAD];
    const float* yr = Y + (size_t)n * ROW;
    for (int i = tid; i < ROW; i += 256)
        accs[(i / Ff) * PAD + (i % Ff)] = yr[i];
    __syncthreads();
    int jj = tid & 63;
    int bb = tid >> 6;   // wave-uniform (0..3)
    float s[4];
    float bias = b1[jj];
#pragma unroll
    for (int w = 0; w < 4; ++w) s[w] = bias;
#pragma unroll 4
    for (int f4 = 0; f4 < 64; f4 += 4) {
        float4 wv;
        wv.x = W1[(f4 + 0) * Uu + jj];
        wv.y = W1[(f4 + 1) * Uu + jj];
        wv.z = W1[(f4 + 2) * Uu + jj];
        wv.w = W1[(f4 + 3) * Uu + jj];
#pragma unroll
        for (int w = 0; w < 4; ++w) {
            float4 av = *(const float4*)(accs + (bb + 4 * w) * PAD + f4);
            s[w] += av.x * wv.x + av.y * wv.y + av.z * wv.z + av.w * wv.w;
        }
    }
    float wt = W1[64 * Uu + jj];
#pragma unroll
    for (int w = 0; w < 4; ++w) s[w] += accs[(bb + 4 * w) * PAD + 64] * wt;
#pragma unroll
    for (int w = 0; w < 4; ++w) {
        int b = bb + 4 * w;
        float cv = tanhf(s[w]);
        size_t off = ((size_t)b * nodes + n) * Uu + jj;
        float u = uo[off];
        uo[off] = u * h[off] + (1.0f - u) * cv;
    }
}

extern "C" void kernel_launch(void* const* d_in, const int* in_sizes, int n_in,
                              void* d_out, int out_size, void* d_ws, size_t ws_size,
                              hipStream_t stream) {
    const float* inputs = (const float*)d_in[0];
    const float* state  = (const float*)d_in[1];
    const float* state1 = (const float*)d_in[2];
    const float* state2 = (const float*)d_in[3];
    const float* A      = (const float*)d_in[4];
    const float* A1     = (const float*)d_in[5];
    const float* adj1   = (const float*)d_in[6];
    const float* afc    = (const float*)d_in[7];
    const float* assM   = (const float*)d_in[8];
    const float* W0  = (const float*)d_in[9];
    const float* b0  = (const float*)d_in[10];
    const float* W1  = (const float*)d_in[11];
    const float* b1  = (const float*)d_in[12];
    const float* W01 = (const float*)d_in[13];
    const float* b01 = (const float*)d_in[14];
    const float* W11 = (const float*)d_in[15];
    const float* b11 = (const float*)d_in[16];
    const float* W02 = (const float*)d_in[17];
    const float* b02 = (const float*)d_in[18];
    const float* W12 = (const float*)d_in[19];
    const float* b12 = (const float*)d_in[20];
    float* out = (float*)d_out;

    char* ws = (char*)d_ws;
    size_t off = 0;
    auto carve = [&](size_t bytes) {
        void* p = ws + off;
        off += (bytes + 255) & ~(size_t)255;
        return p;
    };
    int*   ellA_c  = (int*)  carve((size_t)Nn * CAPF * 4);
    float* ellA_v  = (float*)carve((size_t)Nn * CAPF * 4);
    int*   ellA_n  = (int*)  carve((size_t)Nn * 4);
    int*   ellC_c  = (int*)  carve((size_t)NCc * CAPC * 4);
    float* ellC_v  = (float*)carve((size_t)NCc * CAPC * 4);
    int*   ellC_n  = (int*)  carve((size_t)NCc * 4);
    int*   ellS_c  = (int*)  carve((size_t)NSs * CAPS * 4);
    float* ellS_v  = (float*)carve((size_t)NSs * CAPS * 4);
    int*   ellS_n  = (int*)  carve((size_t)NSs * 4);
    float* Xf      = (float*)carve((size_t)Nn * ROW * 4);
    float* X2f     = (float*)carve((size_t)Nn * ROW * 4);
    float* Ybuf    = (float*)carve((size_t)Nn * ROW * 4);
    float* Xc      = (float*)carve((size_t)NCc * ROW * 4);
    float* X2c     = (float*)carve((size_t)NCc * ROW * 4);
    float* Xs      = (float*)carve((size_t)NSs * ROW * 4);
    float* X2s     = (float*)carve((size_t)NSs * ROW * 4);
    float* xc      = (float*)carve((size_t)Bv * NCc * 4);
    float* Smat    = (float*)carve((size_t)NCc * NSs * 4);
    float* Tmp     = (float*)carve((size_t)NCc * NSs * 4);
    float* Adj2    = (float*)carve((size_t)NSs * NSs * 4);
    float* xs      = (float*)carve((size_t)Bv * NSs * 4);
    if (off > ws_size) return;

    float* out_f = out;                                  // (B, N*U)
    float* out_c = out + (size_t)Bv * Nn * Uu;           // (B, NC*U)
    float* out_s = out_c + (size_t)Bv * NCc * Uu;        // (B, NS*U)

    // 1. sparse builds
    build_ell_v4<<<Nn, 256, 0, stream>>>(A, Nn, CAPF, ellA_c, ellA_v, ellA_n);
    build_ell_v4<<<NCc, 256, 0, stream>>>(A1, NCc, CAPC, ellC_c, ellC_v, ellC_n);
    // 2. pooling path
    xc_kernel<<<NCc, 256, 0, stream>>>(afc, inputs, xc);
    softmax_rows<<<NCc, 64, 0, stream>>>(assM, Smat, NSs);
    mm_tmp<<<(NCc * NSs + 255) / 256, 256, 0, stream>>>(adj1, Smat, Tmp);
    mm_adj2<<<(NSs * NSs + 255) / 256, 256, 0, stream>>>(Smat, Tmp, Adj2);
    build_ell<<<NSs, 256, 0, stream>>>(Adj2, NSs, CAPS, ellS_c, ellS_v, ellS_n);
    mm_xs<<<(Bv * NSs + 255) / 256, 256, 0, stream>>>(Smat, xc, xs);
    // 3. packs
    pack_x<<<((size_t)Nn * ROW + 255) / 256, 256, 0, stream>>>(inputs, state, Xf, Nn);
    pack_x<<<((size_t)NCc * ROW + 255) / 256, 256, 0, stream>>>(xc, state1, Xc, NCc);
    pack_x<<<((size_t)NSs * ROW + 255) / 256, 256, 0, stream>>>(xs, state2, Xs, NSs);
    // 4. fine level: gather / project / gather / project
    spmm_gather<CAPF><<<Nn, 256, 0, stream>>>(Nn, ellA_c, ellA_v, ellA_n, Xf, Ybuf);
    proj_gate<<<Nn, 256, 0, stream>>>(Nn, Ybuf, W0, b0, state, inputs, X2f, out_f);
    spmm_gather<CAPF><<<Nn, 256, 0, stream>>>(Nn, ellA_c, ellA_v, ellA_n, X2f, Ybuf);
    proj_cand<<<Nn, 256, 0, stream>>>(Nn, Ybuf, W1, b1, state, out_f);
    // 5. coarse level
    spmm_gather<CAPC><<<NCc, 256, 0, stream>>>(NCc, ellC_c, ellC_v, ellC_n, Xc, Ybuf);
    proj_gate<<<NCc, 256, 0, stream>>>(NCc, Ybuf, W01, b01, state1, xc, X2c, out_c);
    spmm_gather<CAPC><<<NCc, 256, 0, stream>>>(NCc, ellC_c, ellC_v, ellC_n, X2c, Ybuf);
    proj_cand<<<NCc, 256, 0, stream>>>(NCc, Ybuf, W11, b11, state1, out_c);
    // 6. super level
    spmm_gather<CAPS><<<NSs, 256, 0, stream>>>(NSs, ellS_c, ellS_v, ellS_n, Xs, Ybuf);
    proj_gate<<<NSs, 256, 0, stream>>>(NSs, Ybuf, W02, b02, state2, xs, X2s, out_s);
    spmm_gather<CAPS><<<NSs, 256, 0, stream>>>(NSs, ellS_c, ellS_v, ellS_n, X2s, Ybuf);
    proj_cand<<<NSs, 256, 0, stream>>>(NSs, Ybuf, W12, b12, state2, out_s);
}

// Round 12
// 645.026 us; speedup vs baseline: 1.0426x; 1.0426x over previous
//
#include <hip/hip_runtime.h>
#include <math.h>

#define Bv 16
#define Nn 5000
#define NCc 500
#define NSs 50
#define Uu 64
#define Ff 65   // IN + U
#define CAPF 96
#define CAPC 128
#define CAPS 64
#define ROW  (Bv * Ff)           // 1040 floats per X row
#define ROW4 (ROW / 4)           // 260 float4
#define TAIL4 (ROW4 - 256)       // 4
#define PAD 68                   // padded LDS row (272B, 16B-aligned)

// ---------------- dense -> ELL sparse build (float4 scan; n % 4 == 0) ----------------
__global__ __launch_bounds__(256) void build_ell_v4(const float* __restrict__ A, int n, int cap,
                                                    int* __restrict__ cols, float* __restrict__ vals,
                                                    int* __restrict__ cnt) {
    int row = blockIdx.x;
    __shared__ int scnt;
    if (threadIdx.x == 0) scnt = 0;
    __syncthreads();
    const float4* arow = (const float4*)(A + (size_t)row * n);
    int n4 = n >> 2;
    for (int m = threadIdx.x; m < n4; m += blockDim.x) {
        float4 v = arow[m];
        int base = m << 2;
        if (v.x != 0.0f) { int s = atomicAdd(&scnt, 1); if (s < cap) { cols[(size_t)row * cap + s] = base;     vals[(size_t)row * cap + s] = v.x; } }
        if (v.y != 0.0f) { int s = atomicAdd(&scnt, 1); if (s < cap) { cols[(size_t)row * cap + s] = base + 1; vals[(size_t)row * cap + s] = v.y; } }
        if (v.z != 0.0f) { int s = atomicAdd(&scnt, 1); if (s < cap) { cols[(size_t)row * cap + s] = base + 2; vals[(size_t)row * cap + s] = v.z; } }
        if (v.w != 0.0f) { int s = atomicAdd(&scnt, 1); if (s < cap) { cols[(size_t)row * cap + s] = base + 3; vals[(size_t)row * cap + s] = v.w; } }
    }
    __syncthreads();
    if (threadIdx.x == 0) cnt[row] = scnt < cap ? scnt : cap;
}

// scalar fallback (any n)
__global__ void build_ell(const float* __restrict__ A, int n, int cap,
                          int* __restrict__ cols, float* __restrict__ vals,
                          int* __restrict__ cnt) {
    int row = blockIdx.x;
    __shared__ int scnt;
    if (threadIdx.x == 0) scnt = 0;
    __syncthreads();
    const float* arow = A + (size_t)row * n;
    for (int m = threadIdx.x; m < n; m += blockDim.x) {
        float v = arow[m];
        if (v != 0.0f) {
            int slot = atomicAdd(&scnt, 1);
            if (slot < cap) {
                cols[(size_t)row * cap + slot] = m;
                vals[(size_t)row * cap + slot] = v;
            }
        }
    }
    __syncthreads();
    if (threadIdx.x == 0) cnt[row] = scnt < cap ? scnt : cap;
}

// ---------------- xc[b,c] = sum_n afc[c,n] * xi[b,n] ----------------
__global__ __launch_bounds__(256) void xc_kernel(const float* __restrict__ afc,
                                                 const float* __restrict__ xi,
                                                 float* __restrict__ xc) {
    int c = blockIdx.x;
    float loc[Bv];
#pragma unroll
    for (int b = 0; b < Bv; ++b) loc[b] = 0.0f;
    const float* arow = afc + (size_t)c * Nn;
    for (int n = threadIdx.x; n < Nn; n += blockDim.x) {
        float a = arow[n];
        if (a != 0.0f) {
#pragma unroll
            for (int b = 0; b < Bv; ++b) loc[b] += a * xi[b * Nn + n];
        }
    }
    __shared__ float red[Bv][4];
#pragma unroll
    for (int b = 0; b < Bv; ++b) {
        float v = loc[b];
        for (int off = 32; off; off >>= 1) v += __shfl_down(v, off);
        if ((threadIdx.x & 63) == 0) red[b][threadIdx.x >> 6] = v;
    }
    __syncthreads();
    if (threadIdx.x < Bv) {
        float v = 0.0f;
        for (int w = 0; w < 4; ++w) v += red[threadIdx.x][w];
        xc[threadIdx.x * NCc + c] = v;  // (B, NC)
    }
}

// ---------------- row softmax ----------------
__global__ void softmax_rows(const float* __restrict__ M, float* __restrict__ S,
                             int cols) {
    int r = blockIdx.x;
    int t = threadIdx.x;
    float v = (t < cols) ? M[r * cols + t] : -3.4e38f;
    float m = v;
    for (int off = 32; off; off >>= 1) m = fmaxf(m, __shfl_xor(m, off));
    float e = (t < cols) ? __expf(v - m) : 0.0f;
    float s = e;
    for (int off = 32; off; off >>= 1) s += __shfl_xor(s, off);
    if (t < cols) S[r * cols + t] = e / s;
}

// tmp[c,j] = sum_k adj1[c,k] * S[k,j]
__global__ void mm_tmp(const float* __restrict__ A, const float* __restrict__ S,
                       float* __restrict__ T) {
    int idx = blockIdx.x * blockDim.x + threadIdx.x;
    if (idx >= NCc * NSs) return;
    int r = idx / NSs, c = idx % NSs;
    float s = 0.0f;
    for (int k = 0; k < NCc; ++k) s += A[r * NCc + k] * S[k * NSs + c];
    T[idx] = s;
}
__global__ void mm_adj2(const float* __restrict__ S, const float* __restrict__ T,
                        float* __restrict__ A2) {
    int idx = blockIdx.x * blockDim.x + threadIdx.x;
    if (idx >= NSs * NSs) return;
    int i = idx / NSs, j = idx % NSs;
    float s = 0.0f;
    for (int c = 0; c < NCc; ++c) s += S[c * NSs + i] * T[c * NSs + j];
    A2[idx] = s;
}
__global__ void mm_xs(const float* __restrict__ S, const float* __restrict__ xc,
                      float* __restrict__ xs) {
    int idx = blockIdx.x * blockDim.x + threadIdx.x;
    if (idx >= Bv * NSs) return;
    int b = idx / NSs, j = idx % NSs;
    float s = 0.0f;
    for (int c = 0; c < NCc; ++c) s += S[c * NSs + j] * xc[b * NCc + c];
    xs[idx] = s;
}

// ---------------- pack X[n][b][f] ----------------
__global__ void pack_x(const float* __restrict__ xf, const float* __restrict__ h,
                       float* __restrict__ X, int nodes) {
    int idx = blockIdx.x * blockDim.x + threadIdx.x;
    int total = nodes * Bv * Ff;
    if (idx >= total) return;
    int f = idx % Ff;
    int t = idx / Ff;
    int b = t % Bv;
    int n = t / Bv;
    X[idx] = (f == 0) ? xf[b * nodes + n]
                      : h[(size_t)b * nodes * Uu + n * Uu + (f - 1)];
}

// ==== fused gate: gather A@X into LDS, then x1=Y@W0+b0 ; sig -> r,u ; emit X2,u ====
// Gather body == round-11 spmm_gather (measured); proj body == round-11 proj_gate
// (measured: VGPR 64, occ 38%). Fusion removes the Ybuf round-trip + serialization.
template <int CAP>
__global__ __launch_bounds__(256, 4) void fused_gate(
    int nodes, const int* __restrict__ cols, const float* __restrict__ vals,
    const int* __restrict__ cnt, const float* __restrict__ X,
    const float* __restrict__ W0, const float* __restrict__ b0,
    const float* __restrict__ h, const float* __restrict__ xf,
    float* __restrict__ X2, float* __restrict__ u_out) {
    int n = blockIdx.x;
    int tid = threadIdx.x;
    __shared__ int ncol[CAP];
    __shared__ float nval[CAP];
    __shared__ float accs[Bv * PAD];
    int c = cnt[n];
    for (int j = tid; j < c; j += 256) {
        ncol[j] = cols[(size_t)n * CAP + j];
        nval[j] = vals[(size_t)n * CAP + j];
    }
    __syncthreads();
    // ---- gather phase (== round-11 spmm_gather) ----
    float4 a0 = make_float4(0.f, 0.f, 0.f, 0.f);
    float4 a1 = make_float4(0.f, 0.f, 0.f, 0.f);
#pragma unroll 4
    for (int j = 0; j < c; ++j) {
        const float4* xr4 = (const float4*)(X + (size_t)ncol[j] * ROW);
        float av = nval[j];
        float4 v = xr4[tid];
        a0.x += av * v.x; a0.y += av * v.y; a0.z += av * v.z; a0.w += av * v.w;
        if (tid < TAIL4) {
            float4 v1 = xr4[256 + tid];
            a1.x += av * v1.x; a1.y += av * v1.y; a1.z += av * v1.z; a1.w += av * v1.w;
        }
    }
    // scatter into padded accs (flat i = b*65+f -> accs[b*68+f]; float4 may straddle rows)
    {
        int flat = tid * 4;
        accs[(flat    ) / Ff * PAD + (flat    ) % Ff] = a0.x;
        accs[(flat + 1) / Ff * PAD + (flat + 1) % Ff] = a0.y;
        accs[(flat + 2) / Ff * PAD + (flat + 2) % Ff] = a0.z;
        accs[(flat + 3) / Ff * PAD + (flat + 3) % Ff] = a0.w;
        if (tid < TAIL4) {
            int ft = 1024 + tid * 4;
            accs[(ft    ) / Ff * PAD + (ft    ) % Ff] = a1.x;
            accs[(ft + 1) / Ff * PAD + (ft + 1) % Ff] = a1.y;
            accs[(ft + 2) / Ff * PAD + (ft + 2) % Ff] = a1.z;
            accs[(ft + 3) / Ff * PAD + (ft + 3) % Ff] = a1.w;
        }
    }
    __syncthreads();
    // ---- projection phase (== round-11 proj_gate) ----
    int kk = tid & 127;
    int bb = tid >> 7;   // wave-uniform
    float s[8];
    float bias = b0[kk];
#pragma unroll
    for (int w = 0; w < 8; ++w) s[w] = bias;
#pragma unroll 4
    for (int f4 = 0; f4 < 64; f4 += 4) {
        float4 wv;
        wv.x = W0[(f4 + 0) * 128 + kk];
        wv.y = W0[(f4 + 1) * 128 + kk];
        wv.z = W0[(f4 + 2) * 128 + kk];
        wv.w = W0[(f4 + 3) * 128 + kk];
#pragma unroll
        for (int w = 0; w < 8; ++w) {
            float4 av = *(const float4*)(accs + (bb + 2 * w) * PAD + f4);  // broadcast b128
            s[w] += av.x * wv.x + av.y * wv.y + av.z * wv.z + av.w * wv.w;
        }
    }
    float wt = W0[64 * 128 + kk];
#pragma unroll
    for (int w = 0; w < 8; ++w) s[w] += accs[(bb + 2 * w) * PAD + 64] * wt;
#pragma unroll
    for (int w = 0; w < 8; ++w) {
        int b = bb + 2 * w;
        float sv = 1.0f / (1.0f + __expf(-s[w]));
        if (kk < Uu) {
            float hv = h[((size_t)b * nodes + n) * Uu + kk];
            X2[((size_t)n * Bv + b) * Ff + 1 + kk] = sv * hv;
        } else {
            u_out[((size_t)b * nodes + n) * Uu + (kk - Uu)] = sv;
            if (kk == Uu) X2[((size_t)n * Bv + b) * Ff] = xf[(size_t)b * nodes + n];
        }
    }
}

// ==== fused cand: gather A@X2 into LDS; c=tanh(Y@W1+b1); out=u*h+(1-u)*c ====
template <int CAP>
__global__ __launch_bounds__(256, 4) void fused_cand(
    int nodes, const int* __restrict__ cols, const float* __restrict__ vals,
    const int* __restrict__ cnt, const float* __restrict__ X2,
    const float* __restrict__ W1, const float* __restrict__ b1,
    const float* __restrict__ h, float* __restrict__ uo /* holds u, receives out */) {
    int n = blockIdx.x;
    int tid = threadIdx.x;
    __shared__ int ncol[CAP];
    __shared__ float nval[CAP];
    __shared__ float accs[Bv * PAD];
    int c = cnt[n];
    for (int j = tid; j < c; j += 256) {
        ncol[j] = cols[(size_t)n * CAP + j];
        nval[j] = vals[(size_t)n * CAP + j];
    }
    __syncthreads();
    float4 a0 = make_float4(0.f, 0.f, 0.f, 0.f);
    float4 a1 = make_float4(0.f, 0.f, 0.f, 0.f);
#pragma unroll 4
    for (int j = 0; j < c; ++j) {
        const float4* xr4 = (const float4*)(X2 + (size_t)ncol[j] * ROW);
        float av = nval[j];
        float4 v = xr4[tid];
        a0.x += av * v.x; a0.y += av * v.y; a0.z += av * v.z; a0.w += av * v.w;
        if (tid < TAIL4) {
            float4 v1 = xr4[256 + tid];
            a1.x += av * v1.x; a1.y += av * v1.y; a1.z += av * v1.z; a1.w += av * v1.w;
        }
    }
    {
        int flat = tid * 4;
        accs[(flat    ) / Ff * PAD + (flat    ) % Ff] = a0.x;
        accs[(flat + 1) / Ff * PAD + (flat + 1) % Ff] = a0.y;
        accs[(flat + 2) / Ff * PAD + (flat + 2) % Ff] = a0.z;
        accs[(flat + 3) / Ff * PAD + (flat + 3) % Ff] = a0.w;
        if (tid < TAIL4) {
            int ft = 1024 + tid * 4;
            accs[(ft    ) / Ff * PAD + (ft    ) % Ff] = a1.x;
            accs[(ft + 1) / Ff * PAD + (ft + 1) % Ff] = a1.y;
            accs[(ft + 2) / Ff * PAD + (ft + 2) % Ff] = a1.z;
            accs[(ft + 3) / Ff * PAD + (ft + 3) % Ff] = a1.w;
        }
    }
    __syncthreads();
    int jj = tid & 63;
    int bb = tid >> 6;   // wave-uniform (0..3)
    float s[4];
    float bias = b1[jj];
#pragma unroll
    for (int w = 0; w < 4; ++w) s[w] = bias;
#pragma unroll 4
    for (int f4 = 0; f4 < 64; f4 += 4) {
        float4 wv;
        wv.x = W1[(f4 + 0) * Uu + jj];
        wv.y = W1[(f4 + 1) * Uu + jj];
        wv.z = W1[(f4 + 2) * Uu + jj];
        wv.w = W1[(f4 + 3) * Uu + jj];
#pragma unroll
        for (int w = 0; w < 4; ++w) {
            float4 av = *(const float4*)(accs + (bb + 4 * w) * PAD + f4);
            s[w] += av.x * wv.x + av.y * wv.y + av.z * wv.z + av.w * wv.w;
        }
    }
    float wt = W1[64 * Uu + jj];
#pragma unroll
    for (int w = 0; w < 4; ++w) s[w] += accs[(bb + 4 * w) * PAD + 64] * wt;
#pragma unroll
    for (int w = 0; w < 4; ++w) {
        int b = bb + 4 * w;
        float cv = tanhf(s[w]);
        size_t off = ((size_t)b * nodes + n) * Uu + jj;
        float u = uo[off];
        uo[off] = u * h[off] + (1.0f - u) * cv;
    }
}

extern "C" void kernel_launch(void* const* d_in, const int* in_sizes, int n_in,
                              void* d_out, int out_size, void* d_ws, size_t ws_size,
                              hipStream_t stream) {
    const float* inputs = (const float*)d_in[0];
    const float* state  = (const float*)d_in[1];
    const float* state1 = (const float*)d_in[2];
    const float* state2 = (const float*)d_in[3];
    const float* A      = (const float*)d_in[4];
    const float* A1     = (const float*)d_in[5];
    const float* adj1   = (const float*)d_in[6];
    const float* afc    = (const float*)d_in[7];
    const float* assM   = (const float*)d_in[8];
    const float* W0  = (const float*)d_in[9];
    const float* b0  = (const float*)d_in[10];
    const float* W1  = (const float*)d_in[11];
    const float* b1  = (const float*)d_in[12];
    const float* W01 = (const float*)d_in[13];
    const float* b01 = (const float*)d_in[14];
    const float* W11 = (const float*)d_in[15];
    const float* b11 = (const float*)d_in[16];
    const float* W02 = (const float*)d_in[17];
    const float* b02 = (const float*)d_in[18];
    const float* W12 = (const float*)d_in[19];
    const float* b12 = (const float*)d_in[20];
    float* out = (float*)d_out;

    char* ws = (char*)d_ws;
    size_t off = 0;
    auto carve = [&](size_t bytes) {
        void* p = ws + off;
        off += (bytes + 255) & ~(size_t)255;
        return p;
    };
    int*   ellA_c  = (int*)  carve((size_t)Nn * CAPF * 4);
    float* ellA_v  = (float*)carve((size_t)Nn * CAPF * 4);
    int*   ellA_n  = (int*)  carve((size_t)Nn * 4);
    int*   ellC_c  = (int*)  carve((size_t)NCc * CAPC * 4);
    float* ellC_v  = (float*)carve((size_t)NCc * CAPC * 4);
    int*   ellC_n  = (int*)  carve((size_t)NCc * 4);
    int*   ellS_c  = (int*)  carve((size_t)NSs * CAPS * 4);
    float* ellS_v  = (float*)carve((size_t)NSs * CAPS * 4);
    int*   ellS_n  = (int*)  carve((size_t)NSs * 4);
    float* Xf      = (float*)carve((size_t)Nn * ROW * 4);
    float* X2f     = (float*)carve((size_t)Nn * ROW * 4);
    float* Xc      = (float*)carve((size_t)NCc * ROW * 4);
    float* X2c     = (float*)carve((size_t)NCc * ROW * 4);
    float* Xs      = (float*)carve((size_t)NSs * ROW * 4);
    float* X2s     = (float*)carve((size_t)NSs * ROW * 4);
    float* xc      = (float*)carve((size_t)Bv * NCc * 4);
    float* Smat    = (float*)carve((size_t)NCc * NSs * 4);
    float* Tmp     = (float*)carve((size_t)NCc * NSs * 4);
    float* Adj2    = (float*)carve((size_t)NSs * NSs * 4);
    float* xs      = (float*)carve((size_t)Bv * NSs * 4);
    if (off > ws_size) return;

    float* out_f = out;                                  // (B, N*U)
    float* out_c = out + (size_t)Bv * Nn * Uu;           // (B, NC*U)
    float* out_s = out_c + (size_t)Bv * NCc * Uu;        // (B, NS*U)

    // 1. sparse builds
    build_ell_v4<<<Nn, 256, 0, stream>>>(A, Nn, CAPF, ellA_c, ellA_v, ellA_n);
    build_ell_v4<<<NCc, 256, 0, stream>>>(A1, NCc, CAPC, ellC_c, ellC_v, ellC_n);
    // 2. pooling path
    xc_kernel<<<NCc, 256, 0, stream>>>(afc, inputs, xc);
    softmax_rows<<<NCc, 64, 0, stream>>>(assM, Smat, NSs);
    mm_tmp<<<(NCc * NSs + 255) / 256, 256, 0, stream>>>(adj1, Smat, Tmp);
    mm_adj2<<<(NSs * NSs + 255) / 256, 256, 0, stream>>>(Smat, Tmp, Adj2);
    build_ell<<<NSs, 256, 0, stream>>>(Adj2, NSs, CAPS, ellS_c, ellS_v, ellS_n);
    mm_xs<<<(Bv * NSs + 255) / 256, 256, 0, stream>>>(Smat, xc, xs);
    // 3. packs
    pack_x<<<((size_t)Nn * ROW + 255) / 256, 256, 0, stream>>>(inputs, state, Xf, Nn);
    pack_x<<<((size_t)NCc * ROW + 255) / 256, 256, 0, stream>>>(xc, state1, Xc, NCc);
    pack_x<<<((size_t)NSs * ROW + 255) / 256, 256, 0, stream>>>(xs, state2, Xs, NSs);
    // 4. fine level: fused gather+project ×2
    fused_gate<CAPF><<<Nn, 256, 0, stream>>>(Nn, ellA_c, ellA_v, ellA_n, Xf,
                                             W0, b0, state, inputs, X2f, out_f);
    fused_cand<CAPF><<<Nn, 256, 0, stream>>>(Nn, ellA_c, ellA_v, ellA_n, X2f,
                                             W1, b1, state, out_f);
    // 5. coarse level
    fused_gate<CAPC><<<NCc, 256, 0, stream>>>(NCc, ellC_c, ellC_v, ellC_n, Xc,
                                              W01, b01, state1, xc, X2c, out_c);
    fused_cand<CAPC><<<NCc, 256, 0, stream>>>(NCc, ellC_c, ellC_v, ellC_n, X2c,
                                              W11, b11, state1, out_c);
    // 6. super level
    fused_gate<CAPS><<<NSs, 256, 0, stream>>>(NSs, ellS_c, ellS_v, ellS_n, Xs,
                                              W02, b02, state2, xs, X2s, out_s);
    fused_cand<CAPS><<<NSs, 256, 0, stream>>>(NSs, ellS_c, ellS_v, ellS_n, X2s,
                                              W12, b12, state2, out_s);
}

// Round 14
// 618.890 us; speedup vs baseline: 1.0867x; 1.0422x over previous
//
#include <hip/hip_runtime.h>
#include <hip/hip_fp16.h>
#include <math.h>

#define Bv 16
#define Nn 5000
#define NCc 500
#define NSs 50
#define Uu 64
#define Ff 65   // IN + U
#define CAPF 96
#define CAPC 128
#define CAPS 64
#define ROW  (Bv * Ff)           // 1040 elems per X row
#define ROWC (ROW / 4)           // 260 half4 chunks (8B each)
#define TAILC (ROWC - 256)       // 4
#define PAD 68                   // padded LDS row

struct __align__(8) h4 { __half x, y, z, w; };

// ---------------- dense -> ELL sparse build (float4 scan; n % 4 == 0) ----------------
__global__ __launch_bounds__(256) void build_ell_v4(const float* __restrict__ A, int n, int cap,
                                                    int* __restrict__ cols, float* __restrict__ vals,
                                                    int* __restrict__ cnt) {
    int row = blockIdx.x;
    __shared__ int scnt;
    if (threadIdx.x == 0) scnt = 0;
    __syncthreads();
    const float4* arow = (const float4*)(A + (size_t)row * n);
    int n4 = n >> 2;
    for (int m = threadIdx.x; m < n4; m += blockDim.x) {
        float4 v = arow[m];
        int base = m << 2;
        if (v.x != 0.0f) { int s = atomicAdd(&scnt, 1); if (s < cap) { cols[(size_t)row * cap + s] = base;     vals[(size_t)row * cap + s] = v.x; } }
        if (v.y != 0.0f) { int s = atomicAdd(&scnt, 1); if (s < cap) { cols[(size_t)row * cap + s] = base + 1; vals[(size_t)row * cap + s] = v.y; } }
        if (v.z != 0.0f) { int s = atomicAdd(&scnt, 1); if (s < cap) { cols[(size_t)row * cap + s] = base + 2; vals[(size_t)row * cap + s] = v.z; } }
        if (v.w != 0.0f) { int s = atomicAdd(&scnt, 1); if (s < cap) { cols[(size_t)row * cap + s] = base + 3; vals[(size_t)row * cap + s] = v.w; } }
    }
    __syncthreads();
    if (threadIdx.x == 0) cnt[row] = scnt < cap ? scnt : cap;
}

// scalar fallback (any n)
__global__ void build_ell(const float* __restrict__ A, int n, int cap,
                          int* __restrict__ cols, float* __restrict__ vals,
                          int* __restrict__ cnt) {
    int row = blockIdx.x;
    __shared__ int scnt;
    if (threadIdx.x == 0) scnt = 0;
    __syncthreads();
    const float* arow = A + (size_t)row * n;
    for (int m = threadIdx.x; m < n; m += blockDim.x) {
        float v = arow[m];
        if (v != 0.0f) {
            int slot = atomicAdd(&scnt, 1);
            if (slot < cap) {
                cols[(size_t)row * cap + slot] = m;
                vals[(size_t)row * cap + slot] = v;
            }
        }
    }
    __syncthreads();
    if (threadIdx.x == 0) cnt[row] = scnt < cap ? scnt : cap;
}

// ---------------- xc[b,c] = sum_n afc[c,n] * xi[b,n] ----------------
__global__ __launch_bounds__(256) void xc_kernel(const float* __restrict__ afc,
                                                 const float* __restrict__ xi,
                                                 float* __restrict__ xc) {
    int c = blockIdx.x;
    float loc[Bv];
#pragma unroll
    for (int b = 0; b < Bv; ++b) loc[b] = 0.0f;
    const float* arow = afc + (size_t)c * Nn;
    for (int n = threadIdx.x; n < Nn; n += blockDim.x) {
        float a = arow[n];
        if (a != 0.0f) {
#pragma unroll
            for (int b = 0; b < Bv; ++b) loc[b] += a * xi[b * Nn + n];
        }
    }
    __shared__ float red[Bv][4];
#pragma unroll
    for (int b = 0; b < Bv; ++b) {
        float v = loc[b];
        for (int off = 32; off; off >>= 1) v += __shfl_down(v, off);
        if ((threadIdx.x & 63) == 0) red[b][threadIdx.x >> 6] = v;
    }
    __syncthreads();
    if (threadIdx.x < Bv) {
        float v = 0.0f;
        for (int w = 0; w < 4; ++w) v += red[threadIdx.x][w];
        xc[threadIdx.x * NCc + c] = v;  // (B, NC)
    }
}

// ---------------- row softmax ----------------
__global__ void softmax_rows(const float* __restrict__ M, float* __restrict__ S,
                             int cols) {
    int r = blockIdx.x;
    int t = threadIdx.x;
    float v = (t < cols) ? M[r * cols + t] : -3.4e38f;
    float m = v;
    for (int off = 32; off; off >>= 1) m = fmaxf(m, __shfl_xor(m, off));
    float e = (t < cols) ? __expf(v - m) : 0.0f;
    float s = e;
    for (int off = 32; off; off >>= 1) s += __shfl_xor(s, off);
    if (t < cols) S[r * cols + t] = e / s;
}

// tmp[c,j] = sum_k adj1[c,k] * S[k,j]
__global__ void mm_tmp(const float* __restrict__ A, const float* __restrict__ S,
                       float* __restrict__ T) {
    int idx = blockIdx.x * blockDim.x + threadIdx.x;
    if (idx >= NCc * NSs) return;
    int r = idx / NSs, c = idx % NSs;
    float s = 0.0f;
    for (int k = 0; k < NCc; ++k) s += A[r * NCc + k] * S[k * NSs + c];
    T[idx] = s;
}
__global__ void mm_adj2(const float* __restrict__ S, const float* __restrict__ T,
                        float* __restrict__ A2) {
    int idx = blockIdx.x * blockDim.x + threadIdx.x;
    if (idx >= NSs * NSs) return;
    int i = idx / NSs, j = idx % NSs;
    float s = 0.0f;
    for (int c = 0; c < NCc; ++c) s += S[c * NSs + i] * T[c * NSs + j];
    A2[idx] = s;
}
__global__ void mm_xs(const float* __restrict__ S, const float* __restrict__ xc,
                      float* __restrict__ xs) {
    int idx = blockIdx.x * blockDim.x + threadIdx.x;
    if (idx >= Bv * NSs) return;
    int b = idx / NSs, j = idx % NSs;
    float s = 0.0f;
    for (int c = 0; c < NCc; ++c) s += S[c * NSs + j] * xc[b * NCc + c];
    xs[idx] = s;
}

// ---------------- pack X[n][b][f] -> fp16 ----------------
__global__ void pack_x(const float* __restrict__ xf, const float* __restrict__ h,
                       __half* __restrict__ X, int nodes) {
    int idx = blockIdx.x * blockDim.x + threadIdx.x;
    int total = nodes * Bv * Ff;
    if (idx >= total) return;
    int f = idx % Ff;
    int t = idx / Ff;
    int b = t % Bv;
    int n = t / Bv;
    float v = (f == 0) ? xf[b * nodes + n]
                       : h[(size_t)b * nodes * Uu + n * Uu + (f - 1)];
    X[idx] = __float2half(v);
}

// ==== fused gate: gather A@X(fp16) into LDS(fp32), proj, sigmoid -> X2(fp16), u ====
template <int CAP>
__global__ __launch_bounds__(256, 4) void fused_gate(
    int nodes, const int* __restrict__ cols, const float* __restrict__ vals,
    const int* __restrict__ cnt, const __half* __restrict__ X,
    const float* __restrict__ W0, const float* __restrict__ b0,
    const float* __restrict__ h, const float* __restrict__ xf,
    __half* __restrict__ X2, float* __restrict__ u_out) {
    int n = blockIdx.x;
    int tid = threadIdx.x;
    __shared__ int ncol[CAP];
    __shared__ float nval[CAP];
    __shared__ float accs[Bv * PAD];
    int c = cnt[n];
    for (int j = tid; j < c; j += 256) {
        ncol[j] = cols[(size_t)n * CAP + j];
        nval[j] = vals[(size_t)n * CAP + j];
    }
    __syncthreads();
    // ---- gather phase: half4 (8B) loads, fp32 accumulate ----
    float4 a0 = make_float4(0.f, 0.f, 0.f, 0.f);
    float4 a1 = make_float4(0.f, 0.f, 0.f, 0.f);
#pragma unroll 4
    for (int j = 0; j < c; ++j) {
        const h4* xr = (const h4*)(X + (size_t)ncol[j] * ROW);
        float av = nval[j];
        h4 v = xr[tid];
        a0.x += av * __half2float(v.x); a0.y += av * __half2float(v.y);
        a0.z += av * __half2float(v.z); a0.w += av * __half2float(v.w);
        if (tid < TAILC) {
            h4 v1 = xr[256 + tid];
            a1.x += av * __half2float(v1.x); a1.y += av * __half2float(v1.y);
            a1.z += av * __half2float(v1.z); a1.w += av * __half2float(v1.w);
        }
    }
    // scatter into padded accs (flat i = b*65+f -> accs[b*68+f])
    {
        int flat = tid * 4;
        accs[(flat    ) / Ff * PAD + (flat    ) % Ff] = a0.x;
        accs[(flat + 1) / Ff * PAD + (flat + 1) % Ff] = a0.y;
        accs[(flat + 2) / Ff * PAD + (flat + 2) % Ff] = a0.z;
        accs[(flat + 3) / Ff * PAD + (flat + 3) % Ff] = a0.w;
        if (tid < TAILC) {
            int ft = 1024 + tid * 4;
            accs[(ft    ) / Ff * PAD + (ft    ) % Ff] = a1.x;
            accs[(ft + 1) / Ff * PAD + (ft + 1) % Ff] = a1.y;
            accs[(ft + 2) / Ff * PAD + (ft + 2) % Ff] = a1.z;
            accs[(ft + 3) / Ff * PAD + (ft + 3) % Ff] = a1.w;
        }
    }
    __syncthreads();
    // ---- projection (fp32, == measured round-12) ----
    int kk = tid & 127;
    int bb = tid >> 7;
    float s[8];
    float bias = b0[kk];
#pragma unroll
    for (int w = 0; w < 8; ++w) s[w] = bias;
#pragma unroll 4
    for (int f4 = 0; f4 < 64; f4 += 4) {
        float4 wv;
        wv.x = W0[(f4 + 0) * 128 + kk];
        wv.y = W0[(f4 + 1) * 128 + kk];
        wv.z = W0[(f4 + 2) * 128 + kk];
        wv.w = W0[(f4 + 3) * 128 + kk];
#pragma unroll
        for (int w = 0; w < 8; ++w) {
            float4 av = *(const float4*)(accs + (bb + 2 * w) * PAD + f4);
            s[w] += av.x * wv.x + av.y * wv.y + av.z * wv.z + av.w * wv.w;
        }
    }
    float wt = W0[64 * 128 + kk];
#pragma unroll
    for (int w = 0; w < 8; ++w) s[w] += accs[(bb + 2 * w) * PAD + 64] * wt;
#pragma unroll
    for (int w = 0; w < 8; ++w) {
        int b = bb + 2 * w;
        float sv = 1.0f / (1.0f + __expf(-s[w]));
        if (kk < Uu) {
            float hv = h[((size_t)b * nodes + n) * Uu + kk];
            X2[((size_t)n * Bv + b) * Ff + 1 + kk] = __float2half(sv * hv);
        } else {
            u_out[((size_t)b * nodes + n) * Uu + (kk - Uu)] = sv;
            if (kk == Uu) X2[((size_t)n * Bv + b) * Ff] = __float2half(xf[(size_t)b * nodes + n]);
        }
    }
}

// ==== fused cand: gather A@X2(fp16); c=tanh(Y@W1+b1); out=u*h+(1-u)*c ====
template <int CAP>
__global__ __launch_bounds__(256, 4) void fused_cand(
    int nodes, const int* __restrict__ cols, const float* __restrict__ vals,
    const int* __restrict__ cnt, const __half* __restrict__ X2,
    const float* __restrict__ W1, const float* __restrict__ b1,
    const float* __restrict__ h, float* __restrict__ uo /* holds u, receives out */) {
    int n = blockIdx.x;
    int tid = threadIdx.x;
    __shared__ int ncol[CAP];
    __shared__ float nval[CAP];
    __shared__ float accs[Bv * PAD];
    int c = cnt[n];
    for (int j = tid; j < c; j += 256) {
        ncol[j] = cols[(size_t)n * CAP + j];
        nval[j] = vals[(size_t)n * CAP + j];
    }
    __syncthreads();
    float4 a0 = make_float4(0.f, 0.f, 0.f, 0.f);
    float4 a1 = make_float4(0.f, 0.f, 0.f, 0.f);
#pragma unroll 4
    for (int j = 0; j < c; ++j) {
        const h4* xr = (const h4*)(X2 + (size_t)ncol[j] * ROW);
        float av = nval[j];
        h4 v = xr[tid];
        a0.x += av * __half2float(v.x); a0.y += av * __half2float(v.y);
        a0.z += av * __half2float(v.z); a0.w += av * __half2float(v.w);
        if (tid < TAILC) {
            h4 v1 = xr[256 + tid];
            a1.x += av * __half2float(v1.x); a1.y += av * __half2float(v1.y);
            a1.z += av * __half2float(v1.z); a1.w += av * __half2float(v1.w);
        }
    }
    {
        int flat = tid * 4;
        accs[(flat    ) / Ff * PAD + (flat    ) % Ff] = a0.x;
        accs[(flat + 1) / Ff * PAD + (flat + 1) % Ff] = a0.y;
        accs[(flat + 2) / Ff * PAD + (flat + 2) % Ff] = a0.z;
        accs[(flat + 3) / Ff * PAD + (flat + 3) % Ff] = a0.w;
        if (tid < TAILC) {
            int ft = 1024 + tid * 4;
            accs[(ft    ) / Ff * PAD + (ft    ) % Ff] = a1.x;
            accs[(ft + 1) / Ff * PAD + (ft + 1) % Ff] = a1.y;
            accs[(ft + 2) / Ff * PAD + (ft + 2) % Ff] = a1.z;
            accs[(ft + 3) / Ff * PAD + (ft + 3) % Ff] = a1.w;
        }
    }
    __syncthreads();
    int jj = tid & 63;
    int bb = tid >> 6;
    float s[4];
    float bias = b1[jj];
#pragma unroll
    for (int w = 0; w < 4; ++w) s[w] = bias;
#pragma unroll 4
    for (int f4 = 0; f4 < 64; f4 += 4) {
        float4 wv;
        wv.x = W1[(f4 + 0) * Uu + jj];
        wv.y = W1[(f4 + 1) * Uu + jj];
        wv.z = W1[(f4 + 2) * Uu + jj];
        wv.w = W1[(f4 + 3) * Uu + jj];
#pragma unroll
        for (int w = 0; w < 4; ++w) {
            float4 av = *(const float4*)(accs + (bb + 4 * w) * PAD + f4);
            s[w] += av.x * wv.x + av.y * wv.y + av.z * wv.z + av.w * wv.w;
        }
    }
    float wt = W1[64 * Uu + jj];
#pragma unroll
    for (int w = 0; w < 4; ++w) s[w] += accs[(bb + 4 * w) * PAD + 64] * wt;
#pragma unroll
    for (int w = 0; w < 4; ++w) {
        int b = bb + 4 * w;
        float cv = tanhf(s[w]);
        size_t off = ((size_t)b * nodes + n) * Uu + jj;
        float u = uo[off];
        uo[off] = u * h[off] + (1.0f - u) * cv;
    }
}

extern "C" void kernel_launch(void* const* d_in, const int* in_sizes, int n_in,
                              void* d_out, int out_size, void* d_ws, size_t ws_size,
                              hipStream_t stream) {
    const float* inputs = (const float*)d_in[0];
    const float* state  = (const float*)d_in[1];
    const float* state1 = (const float*)d_in[2];
    const float* state2 = (const float*)d_in[3];
    const float* A      = (const float*)d_in[4];
    const float* A1     = (const float*)d_in[5];
    const float* adj1   = (const float*)d_in[6];
    const float* afc    = (const float*)d_in[7];
    const float* assM   = (const float*)d_in[8];
    const float* W0  = (const float*)d_in[9];
    const float* b0  = (const float*)d_in[10];
    const float* W1  = (const float*)d_in[11];
    const float* b1  = (const float*)d_in[12];
    const float* W01 = (const float*)d_in[13];
    const float* b01 = (const float*)d_in[14];
    const float* W11 = (const float*)d_in[15];
    const float* b11 = (const float*)d_in[16];
    const float* W02 = (const float*)d_in[17];
    const float* b02 = (const float*)d_in[18];
    const float* W12 = (const float*)d_in[19];
    const float* b12 = (const float*)d_in[20];
    float* out = (float*)d_out;

    char* ws = (char*)d_ws;
    size_t off = 0;
    auto carve = [&](size_t bytes) {
        void* p = ws + off;
        off += (bytes + 255) & ~(size_t)255;
        return p;
    };
    int*    ellA_c = (int*)   carve((size_t)Nn * CAPF * 4);
    float*  ellA_v = (float*) carve((size_t)Nn * CAPF * 4);
    int*    ellA_n = (int*)   carve((size_t)Nn * 4);
    int*    ellC_c = (int*)   carve((size_t)NCc * CAPC * 4);
    float*  ellC_v = (float*) carve((size_t)NCc * CAPC * 4);
    int*    ellC_n = (int*)   carve((size_t)NCc * 4);
    int*    ellS_c = (int*)   carve((size_t)NSs * CAPS * 4);
    float*  ellS_v = (float*) carve((size_t)NSs * CAPS * 4);
    int*    ellS_n = (int*)   carve((size_t)NSs * 4);
    __half* Xf     = (__half*)carve((size_t)Nn * ROW * 2);
    __half* X2f    = (__half*)carve((size_t)Nn * ROW * 2);
    __half* Xc     = (__half*)carve((size_t)NCc * ROW * 2);
    __half* X2c    = (__half*)carve((size_t)NCc * ROW * 2);
    __half* Xs     = (__half*)carve((size_t)NSs * ROW * 2);
    __half* X2s    = (__half*)carve((size_t)NSs * ROW * 2);
    float*  xc     = (float*) carve((size_t)Bv * NCc * 4);
    float*  Smat   = (float*) carve((size_t)NCc * NSs * 4);
    float*  Tmp    = (float*) carve((size_t)NCc * NSs * 4);
    float*  Adj2   = (float*) carve((size_t)NSs * NSs * 4);
    float*  xs     = (float*) carve((size_t)Bv * NSs * 4);
    if (off > ws_size) return;

    float* out_f = out;                                  // (B, N*U)
    float* out_c = out + (size_t)Bv * Nn * Uu;           // (B, NC*U)
    float* out_s = out_c + (size_t)Bv * NCc * Uu;        // (B, NS*U)

    // 1. sparse builds
    build_ell_v4<<<Nn, 256, 0, stream>>>(A, Nn, CAPF, ellA_c, ellA_v, ellA_n);
    build_ell_v4<<<NCc, 256, 0, stream>>>(A1, NCc, CAPC, ellC_c, ellC_v, ellC_n);
    // 2. pooling path
    xc_kernel<<<NCc, 256, 0, stream>>>(afc, inputs, xc);
    softmax_rows<<<NCc, 64, 0, stream>>>(assM, Smat, NSs);
    mm_tmp<<<(NCc * NSs + 255) / 256, 256, 0, stream>>>(adj1, Smat, Tmp);
    mm_adj2<<<(NSs * NSs + 255) / 256, 256, 0, stream>>>(Smat, Tmp, Adj2);
    build_ell<<<NSs, 256, 0, stream>>>(Adj2, NSs, CAPS, ellS_c, ellS_v, ellS_n);
    mm_xs<<<(Bv * NSs + 255) / 256, 256, 0, stream>>>(Smat, xc, xs);
    // 3. packs (fp16)
    pack_x<<<((size_t)Nn * ROW + 255) / 256, 256, 0, stream>>>(inputs, state, Xf, Nn);
    pack_x<<<((size_t)NCc * ROW + 255) / 256, 256, 0, stream>>>(xc, state1, Xc, NCc);
    pack_x<<<((size_t)NSs * ROW + 255) / 256, 256, 0, stream>>>(xs, state2, Xs, NSs);
    // 4. fine level
    fused_gate<CAPF><<<Nn, 256, 0, stream>>>(Nn, ellA_c, ellA_v, ellA_n, Xf,
                                             W0, b0, state, inputs, X2f, out_f);
    fused_cand<CAPF><<<Nn, 256, 0, stream>>>(Nn, ellA_c, ellA_v, ellA_n, X2f,
                                             W1, b1, state, out_f);
    // 5. coarse level
    fused_gate<CAPC><<<NCc, 256, 0, stream>>>(NCc, ellC_c, ellC_v, ellC_n, Xc,
                                              W01, b01, state1, xc, X2c, out_c);
    fused_cand<CAPC><<<NCc, 256, 0, stream>>>(NCc, ellC_c, ellC_v, ellC_n, X2c,
                                              W11, b11, state1, out_c);
    // 6. super level
    fused_gate<CAPS><<<NSs, 256, 0, stream>>>(NSs, ellS_c, ellS_v, ellS_n, Xs,
                                              W02, b02, state2, xs, X2s, out_s);
    fused_cand<CAPS><<<NSs, 256, 0, stream>>>(NSs, ellS_c, ellS_v, ellS_n, X2s,
                                              W12, b12, state2, out_s);
}

// Round 15
// 556.380 us; speedup vs baseline: 1.2088x; 1.1124x over previous
//
#include <hip/hip_runtime.h>
#include <hip/hip_fp16.h>
#include <math.h>

#define Bv 16
#define Nn 5000
#define NCc 500
#define NSs 50
#define Uu 64
#define Ff 65   // IN + U
#define CAPF 96
#define CAPC 128
#define CAPS 64
#define ROW  (Bv * Ff)           // 1040 elems per X row
#define ROWC (ROW / 4)           // 260 half4 chunks (8B each)
#define TAILC (ROWC - 256)       // 4
#define PAD 68                   // padded LDS row

struct __align__(8) h4 { __half x, y, z, w; };

// ---------------- dense -> ELL sparse build (float4 scan; n % 4 == 0) ----------------
__global__ __launch_bounds__(256) void build_ell_v4(const float* __restrict__ A, int n, int cap,
                                                    int* __restrict__ cols, float* __restrict__ vals,
                                                    int* __restrict__ cnt) {
    int row = blockIdx.x;
    __shared__ int scnt;
    if (threadIdx.x == 0) scnt = 0;
    __syncthreads();
    const float4* arow = (const float4*)(A + (size_t)row * n);
    int n4 = n >> 2;
    for (int m = threadIdx.x; m < n4; m += blockDim.x) {
        float4 v = arow[m];
        int base = m << 2;
        if (v.x != 0.0f) { int s = atomicAdd(&scnt, 1); if (s < cap) { cols[(size_t)row * cap + s] = base;     vals[(size_t)row * cap + s] = v.x; } }
        if (v.y != 0.0f) { int s = atomicAdd(&scnt, 1); if (s < cap) { cols[(size_t)row * cap + s] = base + 1; vals[(size_t)row * cap + s] = v.y; } }
        if (v.z != 0.0f) { int s = atomicAdd(&scnt, 1); if (s < cap) { cols[(size_t)row * cap + s] = base + 2; vals[(size_t)row * cap + s] = v.z; } }
        if (v.w != 0.0f) { int s = atomicAdd(&scnt, 1); if (s < cap) { cols[(size_t)row * cap + s] = base + 3; vals[(size_t)row * cap + s] = v.w; } }
    }
    __syncthreads();
    if (threadIdx.x == 0) cnt[row] = scnt < cap ? scnt : cap;
}

// scalar fallback (any n)
__global__ void build_ell(const float* __restrict__ A, int n, int cap,
                          int* __restrict__ cols, float* __restrict__ vals,
                          int* __restrict__ cnt) {
    int row = blockIdx.x;
    __shared__ int scnt;
    if (threadIdx.x == 0) scnt = 0;
    __syncthreads();
    const float* arow = A + (size_t)row * n;
    for (int m = threadIdx.x; m < n; m += blockDim.x) {
        float v = arow[m];
        if (v != 0.0f) {
            int slot = atomicAdd(&scnt, 1);
            if (slot < cap) {
                cols[(size_t)row * cap + slot] = m;
                vals[(size_t)row * cap + slot] = v;
            }
        }
    }
    __syncthreads();
    if (threadIdx.x == 0) cnt[row] = scnt < cap ? scnt : cap;
}

// ---------------- xc[b,c] = sum_n afc[c,n] * xi[b,n] ----------------
__global__ __launch_bounds__(256) void xc_kernel(const float* __restrict__ afc,
                                                 const float* __restrict__ xi,
                                                 float* __restrict__ xc) {
    int c = blockIdx.x;
    float loc[Bv];
#pragma unroll
    for (int b = 0; b < Bv; ++b) loc[b] = 0.0f;
    const float* arow = afc + (size_t)c * Nn;
    for (int n = threadIdx.x; n < Nn; n += blockDim.x) {
        float a = arow[n];
        if (a != 0.0f) {
#pragma unroll
            for (int b = 0; b < Bv; ++b) loc[b] += a * xi[b * Nn + n];
        }
    }
    __shared__ float red[Bv][4];
#pragma unroll
    for (int b = 0; b < Bv; ++b) {
        float v = loc[b];
        for (int off = 32; off; off >>= 1) v += __shfl_down(v, off);
        if ((threadIdx.x & 63) == 0) red[b][threadIdx.x >> 6] = v;
    }
    __syncthreads();
    if (threadIdx.x < Bv) {
        float v = 0.0f;
        for (int w = 0; w < 4; ++w) v += red[threadIdx.x][w];
        xc[threadIdx.x * NCc + c] = v;  // (B, NC)
    }
}

// ---------------- row softmax ----------------
__global__ void softmax_rows(const float* __restrict__ M, float* __restrict__ S,
                             int cols) {
    int r = blockIdx.x;
    int t = threadIdx.x;
    float v = (t < cols) ? M[r * cols + t] : -3.4e38f;
    float m = v;
    for (int off = 32; off; off >>= 1) m = fmaxf(m, __shfl_xor(m, off));
    float e = (t < cols) ? __expf(v - m) : 0.0f;
    float s = e;
    for (int off = 32; off; off >>= 1) s += __shfl_xor(s, off);
    if (t < cols) S[r * cols + t] = e / s;
}

// tmp[c,j] = sum_k adj1[c,k] * S[k,j]
__global__ void mm_tmp(const float* __restrict__ A, const float* __restrict__ S,
                       float* __restrict__ T) {
    int idx = blockIdx.x * blockDim.x + threadIdx.x;
    if (idx >= NCc * NSs) return;
    int r = idx / NSs, c = idx % NSs;
    float s = 0.0f;
    for (int k = 0; k < NCc; ++k) s += A[r * NCc + k] * S[k * NSs + c];
    T[idx] = s;
}
__global__ void mm_adj2(const float* __restrict__ S, const float* __restrict__ T,
                        float* __restrict__ A2) {
    int idx = blockIdx.x * blockDim.x + threadIdx.x;
    if (idx >= NSs * NSs) return;
    int i = idx / NSs, j = idx % NSs;
    float s = 0.0f;
    for (int c = 0; c < NCc; ++c) s += S[c * NSs + i] * T[c * NSs + j];
    A2[idx] = s;
}
__global__ void mm_xs(const float* __restrict__ S, const float* __restrict__ xc,
                      float* __restrict__ xs) {
    int idx = blockIdx.x * blockDim.x + threadIdx.x;
    if (idx >= Bv * NSs) return;
    int b = idx / NSs, j = idx % NSs;
    float s = 0.0f;
    for (int c = 0; c < NCc; ++c) s += S[c * NSs + j] * xc[b * NCc + c];
    xs[idx] = s;
}

// ---------------- pack X[n][b][f] -> fp16 ----------------
__global__ void pack_x(const float* __restrict__ xf, const float* __restrict__ h,
                       __half* __restrict__ X, int nodes) {
    int idx = blockIdx.x * blockDim.x + threadIdx.x;
    int total = nodes * Bv * Ff;
    if (idx >= total) return;
    int f = idx % Ff;
    int t = idx / Ff;
    int b = t % Bv;
    int n = t / Bv;
    float v = (f == 0) ? xf[b * nodes + n]
                       : h[(size_t)b * nodes * Uu + n * Uu + (f - 1)];
    X[idx] = __float2half(v);
}

// ==== fused gate: gather A@X(fp16) into LDS(fp32), proj, sigmoid -> X2(fp16), u ====
// (256,8): round-14 measured VGPR=64 at (256,4) with occ 40% — the launch bound,
// not registers, was the occupancy cap. 8 waves/EU doubles gathers in flight.
template <int CAP>
__global__ __launch_bounds__(256, 8) void fused_gate(
    int nodes, const int* __restrict__ cols, const float* __restrict__ vals,
    const int* __restrict__ cnt, const __half* __restrict__ X,
    const float* __restrict__ W0, const float* __restrict__ b0,
    const float* __restrict__ h, const float* __restrict__ xf,
    __half* __restrict__ X2, float* __restrict__ u_out) {
    int n = blockIdx.x;
    int tid = threadIdx.x;
    __shared__ int ncol[CAP];
    __shared__ float nval[CAP];
    __shared__ float accs[Bv * PAD];
    int c = cnt[n];
    for (int j = tid; j < c; j += 256) {
        ncol[j] = cols[(size_t)n * CAP + j];
        nval[j] = vals[(size_t)n * CAP + j];
    }
    __syncthreads();
    // ---- gather phase: half4 (8B) loads, fp32 accumulate ----
    float4 a0 = make_float4(0.f, 0.f, 0.f, 0.f);
    float4 a1 = make_float4(0.f, 0.f, 0.f, 0.f);
#pragma unroll 4
    for (int j = 0; j < c; ++j) {
        const h4* xr = (const h4*)(X + (size_t)ncol[j] * ROW);
        float av = nval[j];
        h4 v = xr[tid];
        a0.x += av * __half2float(v.x); a0.y += av * __half2float(v.y);
        a0.z += av * __half2float(v.z); a0.w += av * __half2float(v.w);
        if (tid < TAILC) {
            h4 v1 = xr[256 + tid];
            a1.x += av * __half2float(v1.x); a1.y += av * __half2float(v1.y);
            a1.z += av * __half2float(v1.z); a1.w += av * __half2float(v1.w);
        }
    }
    // scatter into padded accs (flat i = b*65+f -> accs[b*68+f])
    {
        int flat = tid * 4;
        accs[(flat    ) / Ff * PAD + (flat    ) % Ff] = a0.x;
        accs[(flat + 1) / Ff * PAD + (flat + 1) % Ff] = a0.y;
        accs[(flat + 2) / Ff * PAD + (flat + 2) % Ff] = a0.z;
        accs[(flat + 3) / Ff * PAD + (flat + 3) % Ff] = a0.w;
        if (tid < TAILC) {
            int ft = 1024 + tid * 4;
            accs[(ft    ) / Ff * PAD + (ft    ) % Ff] = a1.x;
            accs[(ft + 1) / Ff * PAD + (ft + 1) % Ff] = a1.y;
            accs[(ft + 2) / Ff * PAD + (ft + 2) % Ff] = a1.z;
            accs[(ft + 3) / Ff * PAD + (ft + 3) % Ff] = a1.w;
        }
    }
    __syncthreads();
    // ---- projection (fp32) ----
    int kk = tid & 127;
    int bb = tid >> 7;
    float s[8];
    float bias = b0[kk];
#pragma unroll
    for (int w = 0; w < 8; ++w) s[w] = bias;
#pragma unroll 4
    for (int f4 = 0; f4 < 64; f4 += 4) {
        float4 wv;
        wv.x = W0[(f4 + 0) * 128 + kk];
        wv.y = W0[(f4 + 1) * 128 + kk];
        wv.z = W0[(f4 + 2) * 128 + kk];
        wv.w = W0[(f4 + 3) * 128 + kk];
#pragma unroll
        for (int w = 0; w < 8; ++w) {
            float4 av = *(const float4*)(accs + (bb + 2 * w) * PAD + f4);
            s[w] += av.x * wv.x + av.y * wv.y + av.z * wv.z + av.w * wv.w;
        }
    }
    float wt = W0[64 * 128 + kk];
#pragma unroll
    for (int w = 0; w < 8; ++w) s[w] += accs[(bb + 2 * w) * PAD + 64] * wt;
#pragma unroll
    for (int w = 0; w < 8; ++w) {
        int b = bb + 2 * w;
        float sv = 1.0f / (1.0f + __expf(-s[w]));
        if (kk < Uu) {
            float hv = h[((size_t)b * nodes + n) * Uu + kk];
            X2[((size_t)n * Bv + b) * Ff + 1 + kk] = __float2half(sv * hv);
        } else {
            u_out[((size_t)b * nodes + n) * Uu + (kk - Uu)] = sv;
            if (kk == Uu) X2[((size_t)n * Bv + b) * Ff] = __float2half(xf[(size_t)b * nodes + n]);
        }
    }
}

// ==== fused cand: gather A@X2(fp16); c=tanh(Y@W1+b1); out=u*h+(1-u)*c ====
template <int CAP>
__global__ __launch_bounds__(256, 8) void fused_cand(
    int nodes, const int* __restrict__ cols, const float* __restrict__ vals,
    const int* __restrict__ cnt, const __half* __restrict__ X2,
    const float* __restrict__ W1, const float* __restrict__ b1,
    const float* __restrict__ h, float* __restrict__ uo /* holds u, receives out */) {
    int n = blockIdx.x;
    int tid = threadIdx.x;
    __shared__ int ncol[CAP];
    __shared__ float nval[CAP];
    __shared__ float accs[Bv * PAD];
    int c = cnt[n];
    for (int j = tid; j < c; j += 256) {
        ncol[j] = cols[(size_t)n * CAP + j];
        nval[j] = vals[(size_t)n * CAP + j];
    }
    __syncthreads();
    float4 a0 = make_float4(0.f, 0.f, 0.f, 0.f);
    float4 a1 = make_float4(0.f, 0.f, 0.f, 0.f);
#pragma unroll 4
    for (int j = 0; j < c; ++j) {
        const h4* xr = (const h4*)(X2 + (size_t)ncol[j] * ROW);
        float av = nval[j];
        h4 v = xr[tid];
        a0.x += av * __half2float(v.x); a0.y += av * __half2float(v.y);
        a0.z += av * __half2float(v.z); a0.w += av * __half2float(v.w);
        if (tid < TAILC) {
            h4 v1 = xr[256 + tid];
            a1.x += av * __half2float(v1.x); a1.y += av * __half2float(v1.y);
            a1.z += av * __half2float(v1.z); a1.w += av * __half2float(v1.w);
        }
    }
    {
        int flat = tid * 4;
        accs[(flat    ) / Ff * PAD + (flat    ) % Ff] = a0.x;
        accs[(flat + 1) / Ff * PAD + (flat + 1) % Ff] = a0.y;
        accs[(flat + 2) / Ff * PAD + (flat + 2) % Ff] = a0.z;
        accs[(flat + 3) / Ff * PAD + (flat + 3) % Ff] = a0.w;
        if (tid < TAILC) {
            int ft = 1024 + tid * 4;
            accs[(ft    ) / Ff * PAD + (ft    ) % Ff] = a1.x;
            accs[(ft + 1) / Ff * PAD + (ft + 1) % Ff] = a1.y;
            accs[(ft + 2) / Ff * PAD + (ft + 2) % Ff] = a1.z;
            accs[(ft + 3) / Ff * PAD + (ft + 3) % Ff] = a1.w;
        }
    }
    __syncthreads();
    int jj = tid & 63;
    int bb = tid >> 6;
    float s[4];
    float bias = b1[jj];
#pragma unroll
    for (int w = 0; w < 4; ++w) s[w] = bias;
#pragma unroll 4
    for (int f4 = 0; f4 < 64; f4 += 4) {
        float4 wv;
        wv.x = W1[(f4 + 0) * Uu + jj];
        wv.y = W1[(f4 + 1) * Uu + jj];
        wv.z = W1[(f4 + 2) * Uu + jj];
        wv.w = W1[(f4 + 3) * Uu + jj];
#pragma unroll
        for (int w = 0; w < 4; ++w) {
            float4 av = *(const float4*)(accs + (bb + 4 * w) * PAD + f4);
            s[w] += av.x * wv.x + av.y * wv.y + av.z * wv.z + av.w * wv.w;
        }
    }
    float wt = W1[64 * Uu + jj];
#pragma unroll
    for (int w = 0; w < 4; ++w) s[w] += accs[(bb + 4 * w) * PAD + 64] * wt;
#pragma unroll
    for (int w = 0; w < 4; ++w) {
        int b = bb + 4 * w;
        float cv = tanhf(s[w]);
        size_t off = ((size_t)b * nodes + n) * Uu + jj;
        float u = uo[off];
        uo[off] = u * h[off] + (1.0f - u) * cv;
    }
}

extern "C" void kernel_launch(void* const* d_in, const int* in_sizes, int n_in,
                              void* d_out, int out_size, void* d_ws, size_t ws_size,
                              hipStream_t stream) {
    const float* inputs = (const float*)d_in[0];
    const float* state  = (const float*)d_in[1];
    const float* state1 = (const float*)d_in[2];
    const float* state2 = (const float*)d_in[3];
    const float* A      = (const float*)d_in[4];
    const float* A1     = (const float*)d_in[5];
    const float* adj1   = (const float*)d_in[6];
    const float* afc    = (const float*)d_in[7];
    const float* assM   = (const float*)d_in[8];
    const float* W0  = (const float*)d_in[9];
    const float* b0  = (const float*)d_in[10];
    const float* W1  = (const float*)d_in[11];
    const float* b1  = (const float*)d_in[12];
    const float* W01 = (const float*)d_in[13];
    const float* b01 = (const float*)d_in[14];
    const float* W11 = (const float*)d_in[15];
    const float* b11 = (const float*)d_in[16];
    const float* W02 = (const float*)d_in[17];
    const float* b02 = (const float*)d_in[18];
    const float* W12 = (const float*)d_in[19];
    const float* b12 = (const float*)d_in[20];
    float* out = (float*)d_out;

    char* ws = (char*)d_ws;
    size_t off = 0;
    auto carve = [&](size_t bytes) {
        void* p = ws + off;
        off += (bytes + 255) & ~(size_t)255;
        return p;
    };
    int*    ellA_c = (int*)   carve((size_t)Nn * CAPF * 4);
    float*  ellA_v = (float*) carve((size_t)Nn * CAPF * 4);
    int*    ellA_n = (int*)   carve((size_t)Nn * 4);
    int*    ellC_c = (int*)   carve((size_t)NCc * CAPC * 4);
    float*  ellC_v = (float*) carve((size_t)NCc * CAPC * 4);
    int*    ellC_n = (int*)   carve((size_t)NCc * 4);
    int*    ellS_c = (int*)   carve((size_t)NSs * CAPS * 4);
    float*  ellS_v = (float*) carve((size_t)NSs * CAPS * 4);
    int*    ellS_n = (int*)   carve((size_t)NSs * 4);
    __half* Xf     = (__half*)carve((size_t)Nn * ROW * 2);
    __half* X2f    = (__half*)carve((size_t)Nn * ROW * 2);
    __half* Xc     = (__half*)carve((size_t)NCc * ROW * 2);
    __half* X2c    = (__half*)carve((size_t)NCc * ROW * 2);
    __half* Xs     = (__half*)carve((size_t)NSs * ROW * 2);
    __half* X2s    = (__half*)carve((size_t)NSs * ROW * 2);
    float*  xc     = (float*) carve((size_t)Bv * NCc * 4);
    float*  Smat   = (float*) carve((size_t)NCc * NSs * 4);
    float*  Tmp    = (float*) carve((size_t)NCc * NSs * 4);
    float*  Adj2   = (float*) carve((size_t)NSs * NSs * 4);
    float*  xs     = (float*) carve((size_t)Bv * NSs * 4);
    if (off > ws_size) return;

    float* out_f = out;                                  // (B, N*U)
    float* out_c = out + (size_t)Bv * Nn * Uu;           // (B, NC*U)
    float* out_s = out_c + (size_t)Bv * NCc * Uu;        // (B, NS*U)

    // 1. sparse builds
    build_ell_v4<<<Nn, 256, 0, stream>>>(A, Nn, CAPF, ellA_c, ellA_v, ellA_n);
    build_ell_v4<<<NCc, 256, 0, stream>>>(A1, NCc, CAPC, ellC_c, ellC_v, ellC_n);
    // 2. pooling path
    xc_kernel<<<NCc, 256, 0, stream>>>(afc, inputs, xc);
    softmax_rows<<<NCc, 64, 0, stream>>>(assM, Smat, NSs);
    mm_tmp<<<(NCc * NSs + 255) / 256, 256, 0, stream>>>(adj1, Smat, Tmp);
    mm_adj2<<<(NSs * NSs + 255) / 256, 256, 0, stream>>>(Smat, Tmp, Adj2);
    build_ell<<<NSs, 256, 0, stream>>>(Adj2, NSs, CAPS, ellS_c, ellS_v, ellS_n);
    mm_xs<<<(Bv * NSs + 255) / 256, 256, 0, stream>>>(Smat, xc, xs);
    // 3. packs (fp16)
    pack_x<<<((size_t)Nn * ROW + 255) / 256, 256, 0, stream>>>(inputs, state, Xf, Nn);
    pack_x<<<((size_t)NCc * ROW + 255) / 256, 256, 0, stream>>>(xc, state1, Xc, NCc);
    pack_x<<<((size_t)NSs * ROW + 255) / 256, 256, 0, stream>>>(xs, state2, Xs, NSs);
    // 4. fine level
    fused_gate<CAPF><<<Nn, 256, 0, stream>>>(Nn, ellA_c, ellA_v, ellA_n, Xf,
                                             W0, b0, state, inputs, X2f, out_f);
    fused_cand<CAPF><<<Nn, 256, 0, stream>>>(Nn, ellA_c, ellA_v, ellA_n, X2f,
                                             W1, b1, state, out_f);
    // 5. coarse level
    fused_gate<CAPC><<<NCc, 256, 0, stream>>>(NCc, ellC_c, ellC_v, ellC_n, Xc,
                                              W01, b01, state1, xc, X2c, out_c);
    fused_cand<CAPC><<<NCc, 256, 0, stream>>>(NCc, ellC_c, ellC_v, ellC_n, X2c,
                                              W11, b11, state1, out_c);
    // 6. super level
    fused_gate<CAPS><<<NSs, 256, 0, stream>>>(NSs, ellS_c, ellS_v, ellS_n, Xs,
                                              W02, b02, state2, xs, X2s, out_s);
    fused_cand<CAPS><<<NSs, 256, 0, stream>>>(NSs, ellS_c, ellS_v, ellS_n, X2s,
                                              W12, b12, state2, out_s);
}

// Round 16
// 446.115 us; speedup vs baseline: 1.5075x; 1.2472x over previous
//
#include <hip/hip_runtime.h>
#include <hip/hip_fp16.h>
#include <math.h>

#define Bv 16
#define Nn 5000
#define NCc 500
#define NSs 50
#define Uu 64
#define Ff 65   // IN + U
#define CAPF 96
#define CAPC 128
#define CAPS 64
#define CAPMAX 128
#define ROW  (Bv * Ff)           // 1040 elems per X row
#define ROWC (ROW / 4)           // 260 half4 chunks
#define TAILC (ROWC - 256)       // 4
#define PAD 68                   // padded LDS row

struct __align__(8) h4 { __half x, y, z, w; };

// ---------------- dense row -> ELL (device helper, float4 path, n%4==0) ----------------
__device__ __forceinline__ void scan_row_v4(const float* __restrict__ arow, int n, int cap,
                                            int* __restrict__ colsRow, float* __restrict__ valsRow,
                                            int* __restrict__ cntSlot, int* scnt) {
    if (threadIdx.x == 0) *scnt = 0;
    __syncthreads();
    const float4* a4 = (const float4*)arow;
    int n4 = n >> 2;
    for (int m = threadIdx.x; m < n4; m += blockDim.x) {
        float4 v = a4[m];
        int base = m << 2;
        if (v.x != 0.0f) { int s = atomicAdd(scnt, 1); if (s < cap) { colsRow[s] = base;     valsRow[s] = v.x; } }
        if (v.y != 0.0f) { int s = atomicAdd(scnt, 1); if (s < cap) { colsRow[s] = base + 1; valsRow[s] = v.y; } }
        if (v.z != 0.0f) { int s = atomicAdd(scnt, 1); if (s < cap) { colsRow[s] = base + 2; valsRow[s] = v.z; } }
        if (v.w != 0.0f) { int s = atomicAdd(scnt, 1); if (s < cap) { colsRow[s] = base + 3; valsRow[s] = v.w; } }
    }
    __syncthreads();
    if (threadIdx.x == 0) *cntSlot = (*scnt < cap) ? *scnt : cap;
}

// merged: rows 0..Nn-1 scan A (cap 96); rows Nn.. scan A1 (cap 128)
__global__ __launch_bounds__(256) void build_ell_2(
    const float* __restrict__ A, const float* __restrict__ A1,
    int* __restrict__ cA, float* __restrict__ vA, int* __restrict__ nA,
    int* __restrict__ cC, float* __restrict__ vC, int* __restrict__ nC) {
    __shared__ int scnt;
    int row = blockIdx.x;
    if (row < Nn)
        scan_row_v4(A + (size_t)row * Nn, Nn, CAPF,
                    cA + (size_t)row * CAPF, vA + (size_t)row * CAPF, nA + row, &scnt);
    else {
        int r = row - Nn;
        scan_row_v4(A1 + (size_t)r * NCc, NCc, CAPC,
                    cC + (size_t)r * CAPC, vC + (size_t)r * CAPC, nC + r, &scnt);
    }
}

// scalar fallback (any n) — used for Adj2 (50x50)
__global__ void build_ell(const float* __restrict__ A, int n, int cap,
                          int* __restrict__ cols, float* __restrict__ vals,
                          int* __restrict__ cnt) {
    int row = blockIdx.x;
    __shared__ int scnt;
    if (threadIdx.x == 0) scnt = 0;
    __syncthreads();
    const float* arow = A + (size_t)row * n;
    for (int m = threadIdx.x; m < n; m += blockDim.x) {
        float v = arow[m];
        if (v != 0.0f) {
            int slot = atomicAdd(&scnt, 1);
            if (slot < cap) {
                cols[(size_t)row * cap + slot] = m;
                vals[(size_t)row * cap + slot] = v;
            }
        }
    }
    __syncthreads();
    if (threadIdx.x == 0) cnt[row] = scnt < cap ? scnt : cap;
}

// ---------------- merged xc (blocks 0..NCc-1) + row softmax (blocks NCc..2NCc-1) ----------------
__global__ __launch_bounds__(256) void xc_softmax(const float* __restrict__ afc,
                                                  const float* __restrict__ xi,
                                                  float* __restrict__ xc,
                                                  const float* __restrict__ M,
                                                  float* __restrict__ S) {
    __shared__ float red[Bv][4];
    if (blockIdx.x < NCc) {
        int c = blockIdx.x;
        float loc[Bv];
#pragma unroll
        for (int b = 0; b < Bv; ++b) loc[b] = 0.0f;
        const float* arow = afc + (size_t)c * Nn;
        for (int n = threadIdx.x; n < Nn; n += blockDim.x) {
            float a = arow[n];
            if (a != 0.0f) {
#pragma unroll
                for (int b = 0; b < Bv; ++b) loc[b] += a * xi[b * Nn + n];
            }
        }
#pragma unroll
        for (int b = 0; b < Bv; ++b) {
            float v = loc[b];
            for (int off = 32; off; off >>= 1) v += __shfl_down(v, off);
            if ((threadIdx.x & 63) == 0) red[b][threadIdx.x >> 6] = v;
        }
        __syncthreads();
        if (threadIdx.x < Bv) {
            float v = 0.0f;
            for (int w = 0; w < 4; ++w) v += red[threadIdx.x][w];
            xc[threadIdx.x * NCc + c] = v;  // (B, NC)
        }
    } else {
        int r = blockIdx.x - NCc;
        int t = threadIdx.x;
        if (t < 64) {
            float v = (t < NSs) ? M[r * NSs + t] : -3.4e38f;
            float m = v;
            for (int off = 32; off; off >>= 1) m = fmaxf(m, __shfl_xor(m, off));
            float e = (t < NSs) ? __expf(v - m) : 0.0f;
            float s = e;
            for (int off = 32; off; off >>= 1) s += __shfl_xor(s, off);
            if (t < NSs) S[r * NSs + t] = e / s;
        }
    }
}

// tmp[c,j] = sum_k adj1[c,k] * S[k,j]
__global__ void mm_tmp(const float* __restrict__ A, const float* __restrict__ S,
                       float* __restrict__ T) {
    int idx = blockIdx.x * blockDim.x + threadIdx.x;
    if (idx >= NCc * NSs) return;
    int r = idx / NSs, c = idx % NSs;
    float s = 0.0f;
    for (int k = 0; k < NCc; ++k) s += A[r * NCc + k] * S[k * NSs + c];
    T[idx] = s;
}

// merged: blocks 0..9 -> adj2[i,j]; blocks 10..13 -> xs[b,j]
__global__ void adj2_xs(const float* __restrict__ S, const float* __restrict__ T,
                        float* __restrict__ A2, const float* __restrict__ xc,
                        float* __restrict__ xs) {
    int blk = blockIdx.x;
    if (blk < 10) {
        int idx = blk * 256 + threadIdx.x;
        if (idx >= NSs * NSs) return;
        int i = idx / NSs, j = idx % NSs;
        float s = 0.0f;
        for (int c = 0; c < NCc; ++c) s += S[c * NSs + i] * T[c * NSs + j];
        A2[idx] = s;
    } else {
        int idx = (blk - 10) * 256 + threadIdx.x;
        if (idx >= Bv * NSs) return;
        int b = idx / NSs, j = idx % NSs;
        float s = 0.0f;
        for (int c = 0; c < NCc; ++c) s += S[c * NSs + j] * xc[b * NCc + c];
        xs[idx] = s;
    }
}

// ---------------- merged pack: all three levels -> fp16 X ----------------
__global__ __launch_bounds__(256) void pack_all(
    const float* __restrict__ inputs, const float* __restrict__ state,
    const float* __restrict__ xcb, const float* __restrict__ state1,
    const float* __restrict__ xsb, const float* __restrict__ state2,
    __half* __restrict__ Xf, __half* __restrict__ Xc, __half* __restrict__ Xs) {
    long idx = (long)blockIdx.x * 256 + threadIdx.x;
    const long NF = (long)Nn * ROW, NC2 = (long)NCc * ROW, NS2 = (long)NSs * ROW;
    const float *xf, *h;
    __half* X;
    int nodes;
    long rel;
    if (idx < NF)              { rel = idx;             xf = inputs; h = state;  X = Xf; nodes = Nn; }
    else if (idx < NF + NC2)   { rel = idx - NF;        xf = xcb;    h = state1; X = Xc; nodes = NCc; }
    else if (idx < NF + NC2 + NS2) { rel = idx - NF - NC2; xf = xsb; h = state2; X = Xs; nodes = NSs; }
    else return;
    int f = (int)(rel % Ff);
    long t2 = rel / Ff;
    int b = (int)(t2 % Bv);
    int n = (int)(t2 / Bv);
    float v = (f == 0) ? xf[b * nodes + n]
                       : h[((size_t)b * nodes + n) * Uu + (f - 1)];
    X[rel] = __float2half(v);
}

// ==== merged fused gate: per-block level select; body == measured round-15 ====
__global__ __launch_bounds__(256, 8) void fused_gate_all(
    const int* __restrict__ cA, const float* __restrict__ vA, const int* __restrict__ nA,
    const int* __restrict__ cC, const float* __restrict__ vC, const int* __restrict__ nC,
    const int* __restrict__ cS, const float* __restrict__ vS, const int* __restrict__ nS,
    const __half* __restrict__ Xf, const __half* __restrict__ Xc, const __half* __restrict__ Xs,
    const float* __restrict__ W0, const float* __restrict__ b0,
    const float* __restrict__ W01, const float* __restrict__ b01,
    const float* __restrict__ W02, const float* __restrict__ b02,
    const float* __restrict__ state, const float* __restrict__ state1, const float* __restrict__ state2,
    const float* __restrict__ inputs, const float* __restrict__ xcb, const float* __restrict__ xsb,
    __half* __restrict__ X2f, __half* __restrict__ X2c, __half* __restrict__ X2s,
    float* __restrict__ out_f, float* __restrict__ out_c, float* __restrict__ out_s) {
    int blk = blockIdx.x;
    int tid = threadIdx.x;
    const int* cols; const float* vals; const int* cntp;
    int cap, nodes, n;
    const __half* X; const float* W; const float* bvec; const float* h; const float* xf;
    __half* X2; float* u_out;
    if (blk < Nn) {
        n = blk; cols = cA; vals = vA; cntp = nA; cap = CAPF; nodes = Nn;
        X = Xf; W = W0; bvec = b0; h = state; xf = inputs; X2 = X2f; u_out = out_f;
    } else if (blk < Nn + NCc) {
        n = blk - Nn; cols = cC; vals = vC; cntp = nC; cap = CAPC; nodes = NCc;
        X = Xc; W = W01; bvec = b01; h = state1; xf = xcb; X2 = X2c; u_out = out_c;
    } else {
        n = blk - Nn - NCc; cols = cS; vals = vS; cntp = nS; cap = CAPS; nodes = NSs;
        X = Xs; W = W02; bvec = b02; h = state2; xf = xsb; X2 = X2s; u_out = out_s;
    }
    __shared__ int ncol[CAPMAX];
    __shared__ float nval[CAPMAX];
    __shared__ float accs[Bv * PAD];
    int c = cntp[n];
    for (int j = tid; j < c; j += 256) {
        ncol[j] = cols[(size_t)n * cap + j];
        nval[j] = vals[(size_t)n * cap + j];
    }
    __syncthreads();
    float4 a0 = make_float4(0.f, 0.f, 0.f, 0.f);
    float4 a1 = make_float4(0.f, 0.f, 0.f, 0.f);
#pragma unroll 4
    for (int j = 0; j < c; ++j) {
        const h4* xr = (const h4*)(X + (size_t)ncol[j] * ROW);
        float av = nval[j];
        h4 v = xr[tid];
        a0.x += av * __half2float(v.x); a0.y += av * __half2float(v.y);
        a0.z += av * __half2float(v.z); a0.w += av * __half2float(v.w);
        if (tid < TAILC) {
            h4 v1 = xr[256 + tid];
            a1.x += av * __half2float(v1.x); a1.y += av * __half2float(v1.y);
            a1.z += av * __half2float(v1.z); a1.w += av * __half2float(v1.w);
        }
    }
    {
        int flat = tid * 4;
        accs[(flat    ) / Ff * PAD + (flat    ) % Ff] = a0.x;
        accs[(flat + 1) / Ff * PAD + (flat + 1) % Ff] = a0.y;
        accs[(flat + 2) / Ff * PAD + (flat + 2) % Ff] = a0.z;
        accs[(flat + 3) / Ff * PAD + (flat + 3) % Ff] = a0.w;
        if (tid < TAILC) {
            int ft = 1024 + tid * 4;
            accs[(ft    ) / Ff * PAD + (ft    ) % Ff] = a1.x;
            accs[(ft + 1) / Ff * PAD + (ft + 1) % Ff] = a1.y;
            accs[(ft + 2) / Ff * PAD + (ft + 2) % Ff] = a1.z;
            accs[(ft + 3) / Ff * PAD + (ft + 3) % Ff] = a1.w;
        }
    }
    __syncthreads();
    int kk = tid & 127;
    int bb = tid >> 7;
    float s[8];
    float bias = bvec[kk];
#pragma unroll
    for (int w = 0; w < 8; ++w) s[w] = bias;
#pragma unroll 4
    for (int f4 = 0; f4 < 64; f4 += 4) {
        float4 wv;
        wv.x = W[(f4 + 0) * 128 + kk];
        wv.y = W[(f4 + 1) * 128 + kk];
        wv.z = W[(f4 + 2) * 128 + kk];
        wv.w = W[(f4 + 3) * 128 + kk];
#pragma unroll
        for (int w = 0; w < 8; ++w) {
            float4 av = *(const float4*)(accs + (bb + 2 * w) * PAD + f4);
            s[w] += av.x * wv.x + av.y * wv.y + av.z * wv.z + av.w * wv.w;
        }
    }
    float wt = W[64 * 128 + kk];
#pragma unroll
    for (int w = 0; w < 8; ++w) s[w] += accs[(bb + 2 * w) * PAD + 64] * wt;
#pragma unroll
    for (int w = 0; w < 8; ++w) {
        int b = bb + 2 * w;
        float sv = 1.0f / (1.0f + __expf(-s[w]));
        if (kk < Uu) {
            float hv = h[((size_t)b * nodes + n) * Uu + kk];
            X2[((size_t)n * Bv + b) * Ff + 1 + kk] = __float2half(sv * hv);
        } else {
            u_out[((size_t)b * nodes + n) * Uu + (kk - Uu)] = sv;
            if (kk == Uu) X2[((size_t)n * Bv + b) * Ff] = __float2half(xf[(size_t)b * nodes + n]);
        }
    }
}

// ==== merged fused cand ====
__global__ __launch_bounds__(256, 8) void fused_cand_all(
    const int* __restrict__ cA, const float* __restrict__ vA, const int* __restrict__ nA,
    const int* __restrict__ cC, const float* __restrict__ vC, const int* __restrict__ nC,
    const int* __restrict__ cS, const float* __restrict__ vS, const int* __restrict__ nS,
    const __half* __restrict__ X2f, const __half* __restrict__ X2c, const __half* __restrict__ X2s,
    const float* __restrict__ W1, const float* __restrict__ b1,
    const float* __restrict__ W11, const float* __restrict__ b11,
    const float* __restrict__ W12, const float* __restrict__ b12,
    const float* __restrict__ state, const float* __restrict__ state1, const float* __restrict__ state2,
    float* __restrict__ out_f, float* __restrict__ out_c, float* __restrict__ out_s) {
    int blk = blockIdx.x;
    int tid = threadIdx.x;
    const int* cols; const float* vals; const int* cntp;
    int cap, nodes, n;
    const __half* X2; const float* W; const float* bvec; const float* h; float* uo;
    if (blk < Nn) {
        n = blk; cols = cA; vals = vA; cntp = nA; cap = CAPF; nodes = Nn;
        X2 = X2f; W = W1; bvec = b1; h = state; uo = out_f;
    } else if (blk < Nn + NCc) {
        n = blk - Nn; cols = cC; vals = vC; cntp = nC; cap = CAPC; nodes = NCc;
        X2 = X2c; W = W11; bvec = b11; h = state1; uo = out_c;
    } else {
        n = blk - Nn - NCc; cols = cS; vals = vS; cntp = nS; cap = CAPS; nodes = NSs;
        X2 = X2s; W = W12; bvec = b12; h = state2; uo = out_s;
    }
    __shared__ int ncol[CAPMAX];
    __shared__ float nval[CAPMAX];
    __shared__ float accs[Bv * PAD];
    int c = cntp[n];
    for (int j = tid; j < c; j += 256) {
        ncol[j] = cols[(size_t)n * cap + j];
        nval[j] = vals[(size_t)n * cap + j];
    }
    __syncthreads();
    float4 a0 = make_float4(0.f, 0.f, 0.f, 0.f);
    float4 a1 = make_float4(0.f, 0.f, 0.f, 0.f);
#pragma unroll 4
    for (int j = 0; j < c; ++j) {
        const h4* xr = (const h4*)(X2 + (size_t)ncol[j] * ROW);
        float av = nval[j];
        h4 v = xr[tid];
        a0.x += av * __half2float(v.x); a0.y += av * __half2float(v.y);
        a0.z += av * __half2float(v.z); a0.w += av * __half2float(v.w);
        if (tid < TAILC) {
            h4 v1 = xr[256 + tid];
            a1.x += av * __half2float(v1.x); a1.y += av * __half2float(v1.y);
            a1.z += av * __half2float(v1.z); a1.w += av * __half2float(v1.w);
        }
    }
    {
        int flat = tid * 4;
        accs[(flat    ) / Ff * PAD + (flat    ) % Ff] = a0.x;
        accs[(flat + 1) / Ff * PAD + (flat + 1) % Ff] = a0.y;
        accs[(flat + 2) / Ff * PAD + (flat + 2) % Ff] = a0.z;
        accs[(flat + 3) / Ff * PAD + (flat + 3) % Ff] = a0.w;
        if (tid < TAILC) {
            int ft = 1024 + tid * 4;
            accs[(ft    ) / Ff * PAD + (ft    ) % Ff] = a1.x;
            accs[(ft + 1) / Ff * PAD + (ft + 1) % Ff] = a1.y;
            accs[(ft + 2) / Ff * PAD + (ft + 2) % Ff] = a1.z;
            accs[(ft + 3) / Ff * PAD + (ft + 3) % Ff] = a1.w;
        }
    }
    __syncthreads();
    int jj = tid & 63;
    int bb = tid >> 6;
    float s[4];
    float bias = bvec[jj];
#pragma unroll
    for (int w = 0; w < 4; ++w) s[w] = bias;
#pragma unroll 4
    for (int f4 = 0; f4 < 64; f4 += 4) {
        float4 wv;
        wv.x = W[(f4 + 0) * Uu + jj];
        wv.y = W[(f4 + 1) * Uu + jj];
        wv.z = W[(f4 + 2) * Uu + jj];
        wv.w = W[(f4 + 3) * Uu + jj];
#pragma unroll
        for (int w = 0; w < 4; ++w) {
            float4 av = *(const float4*)(accs + (bb + 4 * w) * PAD + f4);
            s[w] += av.x * wv.x + av.y * wv.y + av.z * wv.z + av.w * wv.w;
        }
    }
    float wt = W[64 * Uu + jj];
#pragma unroll
    for (int w = 0; w < 4; ++w) s[w] += accs[(bb + 4 * w) * PAD + 64] * wt;
#pragma unroll
    for (int w = 0; w < 4; ++w) {
        int b = bb + 4 * w;
        float cv = tanhf(s[w]);
        size_t off = ((size_t)b * nodes + n) * Uu + jj;
        float u = uo[off];
        uo[off] = u * h[off] + (1.0f - u) * cv;
    }
}

extern "C" void kernel_launch(void* const* d_in, const int* in_sizes, int n_in,
                              void* d_out, int out_size, void* d_ws, size_t ws_size,
                              hipStream_t stream) {
    const float* inputs = (const float*)d_in[0];
    const float* state  = (const float*)d_in[1];
    const float* state1 = (const float*)d_in[2];
    const float* state2 = (const float*)d_in[3];
    const float* A      = (const float*)d_in[4];
    const float* A1     = (const float*)d_in[5];
    const float* adj1   = (const float*)d_in[6];
    const float* afc    = (const float*)d_in[7];
    const float* assM   = (const float*)d_in[8];
    const float* W0  = (const float*)d_in[9];
    const float* b0  = (const float*)d_in[10];
    const float* W1  = (const float*)d_in[11];
    const float* b1  = (const float*)d_in[12];
    const float* W01 = (const float*)d_in[13];
    const float* b01 = (const float*)d_in[14];
    const float* W11 = (const float*)d_in[15];
    const float* b11 = (const float*)d_in[16];
    const float* W02 = (const float*)d_in[17];
    const float* b02 = (const float*)d_in[18];
    const float* W12 = (const float*)d_in[19];
    const float* b12 = (const float*)d_in[20];
    float* out = (float*)d_out;

    char* ws = (char*)d_ws;
    size_t off = 0;
    auto carve = [&](size_t bytes) {
        void* p = ws + off;
        off += (bytes + 255) & ~(size_t)255;
        return p;
    };
    int*    ellA_c = (int*)   carve((size_t)Nn * CAPF * 4);
    float*  ellA_v = (float*) carve((size_t)Nn * CAPF * 4);
    int*    ellA_n = (int*)   carve((size_t)Nn * 4);
    int*    ellC_c = (int*)   carve((size_t)NCc * CAPC * 4);
    float*  ellC_v = (float*) carve((size_t)NCc * CAPC * 4);
    int*    ellC_n = (int*)   carve((size_t)NCc * 4);
    int*    ellS_c = (int*)   carve((size_t)NSs * CAPS * 4);
    float*  ellS_v = (float*) carve((size_t)NSs * CAPS * 4);
    int*    ellS_n = (int*)   carve((size_t)NSs * 4);
    __half* Xf     = (__half*)carve((size_t)Nn * ROW * 2);
    __half* X2f    = (__half*)carve((size_t)Nn * ROW * 2);
    __half* Xc     = (__half*)carve((size_t)NCc * ROW * 2);
    __half* X2c    = (__half*)carve((size_t)NCc * ROW * 2);
    __half* Xs     = (__half*)carve((size_t)NSs * ROW * 2);
    __half* X2s    = (__half*)carve((size_t)NSs * ROW * 2);
    float*  xc     = (float*) carve((size_t)Bv * NCc * 4);
    float*  Smat   = (float*) carve((size_t)NCc * NSs * 4);
    float*  Tmp    = (float*) carve((size_t)NCc * NSs * 4);
    float*  Adj2   = (float*) carve((size_t)NSs * NSs * 4);
    float*  xs     = (float*) carve((size_t)Bv * NSs * 4);
    if (off > ws_size) return;

    float* out_f = out;                                  // (B, N*U)
    float* out_c = out + (size_t)Bv * Nn * Uu;           // (B, NC*U)
    float* out_s = out_c + (size_t)Bv * NCc * Uu;        // (B, NS*U)

    // 1. sparse builds (A + A1 in one launch)
    build_ell_2<<<Nn + NCc, 256, 0, stream>>>(A, A1, ellA_c, ellA_v, ellA_n,
                                              ellC_c, ellC_v, ellC_n);
    // 2. xc + softmax in one launch
    xc_softmax<<<NCc + NCc, 256, 0, stream>>>(afc, inputs, xc, assM, Smat);
    // 3. tmp
    mm_tmp<<<(NCc * NSs + 255) / 256, 256, 0, stream>>>(adj1, Smat, Tmp);
    // 4. adj2 + xs in one launch
    adj2_xs<<<14, 256, 0, stream>>>(Smat, Tmp, Adj2, xc, xs);
    // 5. super ELL
    build_ell<<<NSs, 256, 0, stream>>>(Adj2, NSs, CAPS, ellS_c, ellS_v, ellS_n);
    // 6. pack all levels (fp16)
    {
        long tot = (long)(Nn + NCc + NSs) * ROW;
        pack_all<<<(unsigned)((tot + 255) / 256), 256, 0, stream>>>(
            inputs, state, xc, state1, xs, state2, Xf, Xc, Xs);
    }
    // 7. all gates (fine + coarse + super concurrent)
    fused_gate_all<<<Nn + NCc + NSs, 256, 0, stream>>>(
        ellA_c, ellA_v, ellA_n, ellC_c, ellC_v, ellC_n, ellS_c, ellS_v, ellS_n,
        Xf, Xc, Xs, W0, b0, W01, b01, W02, b02,
        state, state1, state2, inputs, xc, xs,
        X2f, X2c, X2s, out_f, out_c, out_s);
    // 8. all cands
    fused_cand_all<<<Nn + NCc + NSs, 256, 0, stream>>>(
        ellA_c, ellA_v, ellA_n, ellC_c, ellC_v, ellC_n, ellS_c, ellS_v, ellS_n,
        X2f, X2c, X2s, W1, b1, W11, b11, W12, b12,
        state, state1, state2, out_f, out_c, out_s);
}